// Round 10
// baseline (421.532 us; speedup 1.0000x reference)
//
#include <hip/hip_runtime.h>

typedef unsigned short u16;
typedef unsigned int   u32;
typedef __attribute__((ext_vector_type(8))) short  short8;
typedef __attribute__((ext_vector_type(4))) float  f32x4;
typedef __attribute__((ext_vector_type(2))) float  f32x2;
typedef __attribute__((ext_vector_type(2))) unsigned int u32v2;
typedef __attribute__((ext_vector_type(4))) unsigned int u32v4;

#define NN 50000
#define NE 800000

__device__ __forceinline__ float bf2f(u16 b) { return __uint_as_float(((u32)b) << 16); }
__device__ __forceinline__ float bflo(u32 p) { return __uint_as_float(p << 16); }
__device__ __forceinline__ float bfhi(u32 p) { return __uint_as_float(p & 0xffff0000u); }
__device__ __forceinline__ u16 f2bf(float f) {
    u32 u = __float_as_uint(f);
    u32 r = u + 0x7fffu + ((u >> 16) & 1u);
    return (u16)(r >> 16);
}
// leaky-relu + clamped exp (clamp is identity for this data's logit range)
__device__ __forceinline__ float lexp(float v) {
    v = fmaxf(v, 0.2f * v);
    return __expf(fminf(v, 60.f));
}

// block-wide dtype detect (0=bf16, 1=fp32, 2=all-zero) from a 512-word
// prefix; result valid in ALL threads (reduction ends with syncthreads).
__device__ __forceinline__ int block_detect(const u32* x, int n, int* sh, int* sz) {
    int t = threadIdx.x;
    int hits = 0, nz = 0;
    for (int i = t; i < n; i += 256) {
        u32 w = x[i];
        if (w) {
            ++nz;
            u32 e = (w >> 7) & 0xffu;
            if (e >= 100 && e <= 150) ++hits;
        }
    }
    sh[t] = hits; sz[t] = nz;
    __syncthreads();
    for (int ofs = 128; ofs > 0; ofs >>= 1) {
        if (t < ofs) { sh[t] += sh[t + ofs]; sz[t] += sz[t + ofs]; }
        __syncthreads();
    }
    return (sz[0] == 0) ? 2 : ((sh[0] * 2 >= sz[0]) ? 0 : 1);
}

// ---------------------------------------------------------------------------
// k_prep (r10): detect(13) + convert(9) + wpack x3 + deg-zeroing merged into
// ONE launch (replaces the separate hipMemsetAsync too). convert/wpack blocks
// self-detect their source tensor's dtype (same prefix, same rule ->
// identical result, no inter-block dependency).
// ---------------------------------------------------------------------------
struct PrepArgs {
    const u32* dp[13]; int dnw[13];                 // detect
    const void* cs[9]; float* cd[9]; int cn[9];     // convert (n <= 256)
    const void* wsrc[3]; u16* wdst[3]; int wN[3]; int wchunks[3];  // wpack
    int* deg; int degn;                             // deg zeroing
};

__global__ __launch_bounds__(256) void k_prep(PrepArgs a, int* flags) {
    __shared__ int sh[256], sz[256];
    const int bid = blockIdx.x;
    const int t = threadIdx.x;
    if (bid < 13) {
        int f = block_detect(a.dp[bid], a.dnw[bid], sh, sz);
        if (t == 0) flags[bid] = f;
    } else if (bid < 22) {
        const int j = bid - 13;
        int nw = a.cn[j] / 2; if (nw > 512) nw = 512;
        const int fl = block_detect((const u32*)a.cs[j], nw, sh, sz);
        if (t < a.cn[j]) {
            float v = 0.f;
            if (fl == 1) v = ((const float*)a.cs[j])[t];
            else if (fl == 0) v = bf2f(((const u16*)a.cs[j])[t]);
            a.cd[j][t] = v;
        }
    } else if (bid < 90) {
        int wj, base;
        if (bid < 54)      { wj = 0; base = 22; }
        else if (bid < 86) { wj = 1; base = 54; }
        else               { wj = 2; base = 86; }
        const void* Wsrc = a.wsrc[wj];
        const int fl = block_detect((const u32*)Wsrc, 512, sh, sz);
        const int id = (bid - base) * 256 + t;
        if (id < a.wchunks[wj]) {
            const int L = id & 63, kt = (id >> 6) & 7, nt = id >> 9;
            const int col = nt * 16 + (L & 15);
            const int krow = kt * 32 + ((L >> 4) & 3) * 8;
            const bool isf32 = (fl == 1);
            const int N = a.wN[wj];
            u16* Wp = a.wdst[wj];
#pragma unroll
            for (int j2 = 0; j2 < 8; ++j2) {
                int s = (krow + j2) * N + col;
                Wp[id * 8 + j2] = isf32 ? f2bf(((const float*)Wsrc)[s])
                                        : ((const u16*)Wsrc)[s];
            }
        }
    } else {
        const int i = (bid - 90) * 256 + t;
        if (i < a.degn) a.deg[i] = 0;
    }
}

// ---------------------------------------------------------------------------
// CSR build (graph static across layers) — 3-phase multi-block scan
// ---------------------------------------------------------------------------
__global__ void k_hist(const int* __restrict__ dst, int* __restrict__ deg, int E) {
    int e = blockIdx.x * 256 + threadIdx.x;
    if (e < E) atomicAdd(&deg[dst[e]], 1);
}

__global__ __launch_bounds__(256) void k_scan_partial(const int* __restrict__ deg,
                                                      int* __restrict__ bsum, int n) {
    __shared__ int red[256];
    int t = threadIdx.x;
    int i = blockIdx.x * 256 + t;
    red[t] = (i < n) ? deg[i] : 0;
    __syncthreads();
    for (int ofs = 128; ofs > 0; ofs >>= 1) {
        if (t < ofs) red[t] += red[t + ofs];
        __syncthreads();
    }
    if (t == 0) bsum[blockIdx.x] = red[0];
}

__global__ __launch_bounds__(256) void k_scan_bsum(int* __restrict__ bsum, int nb) {
    __shared__ int s[256];
    int t = threadIdx.x;
    int v = (t < nb) ? bsum[t] : 0;
    s[t] = v;
    __syncthreads();
    for (int ofs = 1; ofs < 256; ofs <<= 1) {
        int x = (t >= ofs) ? s[t - ofs] : 0;
        __syncthreads();
        s[t] += x;
        __syncthreads();
    }
    if (t < nb) bsum[t] = s[t] - v;   // exclusive
}

__global__ __launch_bounds__(256) void k_scan_final(const int* __restrict__ deg,
                                                    const int* __restrict__ bsum,
                                                    int* __restrict__ rowptr,
                                                    int* __restrict__ cursor, int n) {
    __shared__ int s[256];
    int t = threadIdx.x;
    int i = blockIdx.x * 256 + t;
    int v = (i < n) ? deg[i] : 0;
    s[t] = v;
    __syncthreads();
    for (int ofs = 1; ofs < 256; ofs <<= 1) {
        int x = (t >= ofs) ? s[t - ofs] : 0;
        __syncthreads();
        s[t] += x;
        __syncthreads();
    }
    int excl = bsum[blockIdx.x] + s[t] - v;
    if (i < n) {
        rowptr[i] = excl;
        cursor[i] = excl;
        if (i == n - 1) rowptr[n] = excl + v;
    }
}

__global__ void k_scatter(const int* __restrict__ src, const int* __restrict__ dst,
                          int* __restrict__ cursor, int* __restrict__ csr_src, int E) {
    int e = blockIdx.x * 256 + threadIdx.x;
    if (e >= E) return;
    int p = atomicAdd(&cursor[dst[e]], 1);
    csr_src[p] = src[e];
}

// ---------------------------------------------------------------------------
// MFMA GEMM (FULL-WIDTH, r9): [nrows,256] x Wp -> bf16 OUT [nrows,256],
// 512 threads / 8 waves per block, grid (nrows/64). X staged ONCE.
// As staging XOR-swizzled (bank-conflict fix, r2).
// ---------------------------------------------------------------------------
__global__ __launch_bounds__(512) void k_gemm_mfma(const void* __restrict__ Xv,
                                                   const int* __restrict__ xflag,
                                                   const u16* __restrict__ Wp,
                                                   u16* __restrict__ OUT, int nrows) {
    __shared__ u16 As[64 * 256];   // 32 KB
    const int t = threadIdx.x;
    const int w = t >> 6, L = t & 63;
    const int quad = (L >> 4) & 3;
    const int r0 = blockIdx.x * 64;
    const bool xf32 = (xflag != nullptr) && (*xflag == 1);

    short8* Asv = (short8*)As;
    short8 zero = {0, 0, 0, 0, 0, 0, 0, 0};
#pragma unroll
    for (int i = 0; i < 4; ++i) {
        int g = i * 512 + t;
        int row = g >> 5, cc = g & 31;
        int r = r0 + row;
        short8 val = zero;
        if (r < nrows) {
            if (xf32) {
                const f32x4* Xf4 = (const f32x4*)Xv;
                f32x4 lo = Xf4[(size_t)r * 64 + cc * 2];
                f32x4 hi = Xf4[(size_t)r * 64 + cc * 2 + 1];
                val[0] = (short)f2bf(lo[0]); val[1] = (short)f2bf(lo[1]);
                val[2] = (short)f2bf(lo[2]); val[3] = (short)f2bf(lo[3]);
                val[4] = (short)f2bf(hi[0]); val[5] = (short)f2bf(hi[1]);
                val[6] = (short)f2bf(hi[2]); val[7] = (short)f2bf(hi[3]);
            } else {
                val = ((const short8*)Xv)[(size_t)r * 32 + cc];
            }
        }
        Asv[cc * 64 + (row ^ (cc & 7))] = val;
    }

    const short8* Wv = (const short8*)Wp;
    short8 bf[2][8];
#pragma unroll
    for (int jn = 0; jn < 2; ++jn) {
        int nt = w + jn * 8;
#pragma unroll
        for (int kt = 0; kt < 8; ++kt) bf[jn][kt] = Wv[(nt * 8 + kt) * 64 + L];
    }
    __syncthreads();

    f32x4 acc[4][2];
#pragma unroll
    for (int mi = 0; mi < 4; ++mi)
#pragma unroll
        for (int jn = 0; jn < 2; ++jn) acc[mi][jn] = (f32x4){0.f, 0.f, 0.f, 0.f};

#pragma unroll
    for (int kt = 0; kt < 8; ++kt) {
        const int ccr = kt * 4 + quad;
#pragma unroll
        for (int mi = 0; mi < 4; ++mi) {
            short8 af = Asv[ccr * 64 + ((mi * 16 + (L & 15)) ^ (ccr & 7))];
            acc[mi][0] = __builtin_amdgcn_mfma_f32_16x16x32_bf16(af, bf[0][kt], acc[mi][0], 0, 0, 0);
            acc[mi][1] = __builtin_amdgcn_mfma_f32_16x16x32_bf16(af, bf[1][kt], acc[mi][1], 0, 0, 0);
        }
    }

#pragma unroll
    for (int mi = 0; mi < 4; ++mi) {
        int rb = r0 + mi * 16 + quad * 4;
#pragma unroll
        for (int jn = 0; jn < 2; ++jn) {
            int c = (w + jn * 8) * 16 + (L & 15);
#pragma unroll
            for (int reg = 0; reg < 4; ++reg) {
                int r = rb + reg;
                if (r < nrows) OUT[(size_t)r * 256 + c] = f2bf(acc[mi][jn][reg]);
            }
        }
    }
}

// MFMA GEMM layer 2: [nrows,256](bf16) x Wp2 -> bf16 [nrows,32]. BM=128, BN=32.
__global__ __launch_bounds__(256) void k_gemm_mfma32(const u16* __restrict__ Xb,
                                                     const u16* __restrict__ Wp,
                                                     u16* __restrict__ OUT, int nrows) {
    __shared__ u16 As[128 * 256];  // 64 KB
    const int t = threadIdx.x;
    const int w = t >> 6, L = t & 63;
    const int quad = (L >> 4) & 3;
    const int r0 = blockIdx.x * 128;
    const int mh = (w >> 1) * 64, nt = w & 1;

    const short8* Xv = (const short8*)Xb;
    short8* Asv = (short8*)As;
    short8 zero = {0, 0, 0, 0, 0, 0, 0, 0};
#pragma unroll
    for (int i = 0; i < 16; ++i) {
        int g = i * 256 + t;
        int row = g >> 5, cc = g & 31;
        int r = r0 + row;
        Asv[cc * 128 + (row ^ (cc & 7))] = (r < nrows) ? Xv[(size_t)r * 32 + cc] : zero;
    }

    const short8* Wv = (const short8*)Wp;
    short8 bf[8];
#pragma unroll
    for (int kt = 0; kt < 8; ++kt) bf[kt] = Wv[(nt * 8 + kt) * 64 + L];
    __syncthreads();

    f32x4 acc[4];
#pragma unroll
    for (int mi = 0; mi < 4; ++mi) acc[mi] = (f32x4){0.f, 0.f, 0.f, 0.f};

#pragma unroll
    for (int kt = 0; kt < 8; ++kt) {
        const int ccr = kt * 4 + quad;
#pragma unroll
        for (int mi = 0; mi < 4; ++mi) {
            short8 af = Asv[ccr * 128 + ((mh + mi * 16 + (L & 15)) ^ (ccr & 7))];
            acc[mi] = __builtin_amdgcn_mfma_f32_16x16x32_bf16(af, bf[kt], acc[mi], 0, 0, 0);
        }
    }

#pragma unroll
    for (int mi = 0; mi < 4; ++mi) {
        int rb = r0 + mh + mi * 16 + quad * 4;
        int c = nt * 16 + (L & 15);
#pragma unroll
        for (int reg = 0; reg < 4; ++reg) {
            int r = rb + reg;
            if (r < nrows) OUT[(size_t)r * 32 + c] = f2bf(acc[mi][reg]);
        }
    }
}

// attention logit dots (feat bf16 node-major, dwordx4 loads)
__global__ void k_elr8(const u16* __restrict__ featb, const float* __restrict__ al,
                       const float* __restrict__ ar, float* __restrict__ el,
                       float* __restrict__ er, int n) {
    int idx = blockIdx.x * 256 + threadIdx.x;
    if (idx >= n * 8) return;
    int node = idx >> 3, h = idx & 7;
    const u32v4* fu = (const u32v4*)((const u32*)featb + (size_t)node * 128 + h * 16);
    const float* A = al + h * 32;
    const float* B = ar + h * 32;
    float sl = 0.f, sr = 0.f;
#pragma unroll
    for (int j = 0; j < 4; ++j) {
        u32v4 w4 = fu[j];
#pragma unroll
        for (int k = 0; k < 4; ++k) {
            u32 w = (k == 0) ? w4.x : (k == 1) ? w4.y : (k == 2) ? w4.z : w4.w;
            float f0 = bflo(w), f1 = bfhi(w);
            int c = j * 8 + k * 2;
            sl += f0 * A[c] + f1 * A[c + 1];
            sr += f0 * B[c] + f1 * B[c + 1];
        }
    }
    el[idx] = sl;
    er[idx] = sr;
}

__global__ void k_elr1(const u16* __restrict__ featb, const float* __restrict__ al,
                       const float* __restrict__ ar, float* __restrict__ el,
                       float* __restrict__ er, int n) {
    int node = blockIdx.x * 256 + threadIdx.x;
    if (node >= n) return;
    const u32v4* fu = (const u32v4*)((const u32*)featb + (size_t)node * 16);
    float sl = 0.f, sr = 0.f;
#pragma unroll
    for (int j = 0; j < 4; ++j) {
        u32v4 w4 = fu[j];
#pragma unroll
        for (int k = 0; k < 4; ++k) {
            u32 w = (k == 0) ? w4.x : (k == 1) ? w4.y : (k == 2) ? w4.z : w4.w;
            float f0 = bflo(w), f1 = bfhi(w);
            int c = j * 8 + k * 2;
            sl += f0 * al[c] + f1 * al[c + 1];
            sr += f0 * ar[c] + f1 * ar[c + 1];
        }
    }
    el[node] = sl;
    er[node] = sr;
}

// ---------------------------------------------------------------------------
// fused softmax+gather: ONE WAVE PER NODE (64 lanes x dwordx2 = 4 cols/lane),
// software-pipelined 8-edge chunks (the MEASURED-BEST r1 kernel, verbatim:
// 65.5us @ 209MB / 3.67TB/s = the random-512B-chunk L3->L2 fill ceiling;
// head-sliced L2-resident variants cut FETCH to 33MB but paid more in
// per-(edge,head) issue cost — 99-130us. Do not re-litigate without a new
// mechanism for BOTH traffic and issue amortization.)
// ---------------------------------------------------------------------------
__global__ __launch_bounds__(256) void k_gather8(const int* __restrict__ rowptr,
                                                 const int* __restrict__ csr_src,
                                                 const float* __restrict__ el,
                                                 const float* __restrict__ er,
                                                 const u32v2* __restrict__ featb4,
                                                 const float* __restrict__ bias,
                                                 u32v2* __restrict__ xout4) {
    __shared__ __align__(16) float sAL[4][2][64];   // [wave][buf][h*8+e]
    __shared__ __align__(16) int   sSL[4][2][8];    // [wave][buf][e]
    const int t = threadIdx.x;
    const int wv = t >> 6;
    const int q = t & 63;            // owns cols 4q..4q+3, head h = q>>3
    const int d = blockIdx.x * 4 + wv;
    const int eL = q >> 3, hL = q & 7;   // producer role: edge eL, head hL
    const int b = rowptr[d], e = rowptr[d + 1];
    const int deg = e - b;
    const int nch = (deg + 7) >> 3;
    const float erA = er[d * 8 + hL];

    float (*AL)[64] = sAL[wv];
    int (*SL)[8] = sSL[wv];

    float a0 = 0.f, a1 = 0.f, a2 = 0.f, a3 = 0.f;
    float partial = 0.f;

    u32v2 fw[8], fw2[8];
    int csrP = 0, ncP = 0;
    float elP = 0.f;

    if (nch > 0) {
        // prologue: stage chunk 0 fully; issue chunk-1 csr + el
        const int nc0 = deg < 8 ? deg : 8;
        const int i0 = eL < nc0 ? eL : nc0 - 1;
        const int s0 = csr_src[b + i0];
        if (nch > 1) {
            const int r1 = deg - 8;
            ncP = r1 < 8 ? r1 : 8;
            const int i1 = eL < ncP ? eL : ncP - 1;
            csrP = csr_src[b + 8 + i1];
        }
        const float el0 = el[s0 * 8 + hL];
        if (hL == 0) SL[0][eL] = s0;
        const int4 sv0 = *(const int4*)&SL[0][0];
        const int4 sv1 = *(const int4*)&SL[0][4];
        fw[0] = featb4[sv0.x * 64 + q];
        fw[1] = featb4[sv0.y * 64 + q];
        fw[2] = featb4[sv0.z * 64 + q];
        fw[3] = featb4[sv0.w * 64 + q];
        fw[4] = featb4[sv1.x * 64 + q];
        fw[5] = featb4[sv1.y * 64 + q];
        fw[6] = featb4[sv1.z * 64 + q];
        fw[7] = featb4[sv1.w * 64 + q];
        const float ex0 = (eL < nc0) ? lexp(el0 + erA) : 0.f;
        partial += ex0;
        AL[0][hL * 8 + eL] = ex0;
        if (nch > 1) elP = el[csrP * 8 + hL];
    }

    for (int c = 0; c < nch; ++c) {
        const int cur = c & 1, nxt = cur ^ 1;

        // issue csr for chunk c+2 (2-deep so c+1's el issue never stalls)
        int csrF = 0, ncF = 0;
        if (c + 2 < nch) {
            const int r2 = deg - (c + 2) * 8;
            ncF = r2 < 8 ? r2 : 8;
            const int i2 = eL < ncF ? eL : ncF - 1;
            csrF = csr_src[b + (c + 2) * 8 + i2];
        }

        // stage chunk c+1: s-list -> LDS -> feat issues; alpha -> LDS
        if (c + 1 < nch) {
            if (hL == 0) SL[nxt][eL] = csrP;
            const int4 sv0 = *(const int4*)&SL[nxt][0];
            const int4 sv1 = *(const int4*)&SL[nxt][4];
            fw2[0] = featb4[sv0.x * 64 + q];
            fw2[1] = featb4[sv0.y * 64 + q];
            fw2[2] = featb4[sv0.z * 64 + q];
            fw2[3] = featb4[sv0.w * 64 + q];
            fw2[4] = featb4[sv1.x * 64 + q];
            fw2[5] = featb4[sv1.y * 64 + q];
            fw2[6] = featb4[sv1.z * 64 + q];
            fw2[7] = featb4[sv1.w * 64 + q];
            const float exN = (eL < ncP) ? lexp(elP + erA) : 0.f;
            partial += exN;
            AL[nxt][hL * 8 + eL] = exN;
        }

        // read alpha chunk c (broadcast ds_read_b128 x2, conflict-free)
        const int h8 = (q >> 3) * 8;
        const f32x4 A0 = *(const f32x4*)&AL[cur][h8];
        const f32x4 A1 = *(const f32x4*)&AL[cur][h8 + 4];

        // issue el for chunk c+2 (elP consumed above; safe to overwrite)
        if (c + 2 < nch) elP = el[csrF * 8 + hL];

        // FMA chunk c (feat issued one full chunk ago -> latency hidden)
#define GAT_EDGE(i, axv) { const u32v2 w_ = fw[i]; \
        a0 += bflo(w_.x) * (axv); a1 += bfhi(w_.x) * (axv); \
        a2 += bflo(w_.y) * (axv); a3 += bfhi(w_.y) * (axv); }
        GAT_EDGE(0, A0[0]) GAT_EDGE(1, A0[1]) GAT_EDGE(2, A0[2]) GAT_EDGE(3, A0[3])
        GAT_EDGE(4, A1[0]) GAT_EDGE(5, A1[1]) GAT_EDGE(6, A1[2]) GAT_EDGE(7, A1[3])
#undef GAT_EDGE

        // rotate pipeline state
#pragma unroll
        for (int i = 0; i < 8; ++i) fw[i] = fw2[i];
        csrP = csrF;
        ncP = ncF;
    }

    // denominator: reduce producer partials across eL (bits 3..5), then
    // fetch the consumer head's sum from lane (q>>3)
    float v = partial;
    v += __shfl_xor(v, 8);
    v += __shfl_xor(v, 16);
    v += __shfl_xor(v, 32);
    const float ssd = __shfl(v, q >> 3);

    const float rd = 1.f / (ssd + 1e-9f);
    const float4 bb = *(const float4*)&bias[4 * q];
    float v0 = a0 * rd + bb.x;
    float v1 = a1 * rd + bb.y;
    float v2 = a2 * rd + bb.z;
    float v3 = a3 * rd + bb.w;
    v0 = v0 > 0.f ? v0 : expm1f(v0);
    v1 = v1 > 0.f ? v1 : expm1f(v1);
    v2 = v2 > 0.f ? v2 : expm1f(v2);
    v3 = v3 > 0.f ? v3 : expm1f(v3);
    u32v2 o;
    o.x = (u32)f2bf(v0) | ((u32)f2bf(v1) << 16);
    o.y = (u32)f2bf(v2) | ((u32)f2bf(v3) << 16);
    xout4[(size_t)d * 64 + q] = o;
}

// ---------------------------------------------------------------------------
// layer-2 fused gather (r10: PIPELINED): was the last r0-style serial kernel
// (4-edge dependent chains, no prefetch) — prime suspect in the 287us
// mid-tier. New: 16 lanes/node, constant-16-slot chunks; each lane owns one
// edge's csr/el/lexp (computed once), (s,alpha) broadcast via __shfl(.,i,16),
// 16 independent feat loads per chunk (featb slice 3.2MB -> L2-resident per
// XCD; r3 proved this exact structure correct). Tail: clamp csr (hot line),
// alpha=0.
// ---------------------------------------------------------------------------
__global__ __launch_bounds__(256) void k_gather1(const int* __restrict__ rowptr,
                                                 const int* __restrict__ csr_src,
                                                 const float* __restrict__ el,
                                                 const float* __restrict__ er,
                                                 const u32* __restrict__ featb2,
                                                 const float* __restrict__ bias,
                                                 void* __restrict__ out,
                                                 const int* __restrict__ flag, int n) {
    const int t = threadIdx.x;
    const int d = blockIdx.x * 16 + (t >> 4);
    const int lane = t & 15;          // owns cols 2*lane, 2*lane+1
    if (d >= n) return;
    const int b = rowptr[d], e = rowptr[d + 1];
    const float erd = er[d];
    float a0 = 0.f, a1 = 0.f, ssum = 0.f;

    for (int c = b; c < e; c += 16) {
        const int idx = c + lane;
        // clamp keeps the load valid & line-hot; alpha forced to 0 on tail
        const int s_own = csr_src[idx < e ? idx : e - 1];
        const float ex_own = (idx < e) ? lexp(el[s_own] + erd) : 0.f;
        ssum += ex_own;
#pragma unroll
        for (int i = 0; i < 16; ++i) {
            const int si = __shfl(s_own, i, 16);
            const float ai = __shfl(ex_own, i, 16);
            const u32 w = featb2[(size_t)si * 16 + lane];
            a0 += bflo(w) * ai;
            a1 += bfhi(w) * ai;
        }
    }

    // denominator: reduce across the 16-lane group (xor stays in-group)
    ssum += __shfl_xor(ssum, 1);
    ssum += __shfl_xor(ssum, 2);
    ssum += __shfl_xor(ssum, 4);
    ssum += __shfl_xor(ssum, 8);

    const float rd = 1.f / (ssum + 1e-9f);
    const float v0 = a0 * rd + bias[2 * lane];
    const float v1 = a1 * rd + bias[2 * lane + 1];
    if (*flag == 1) {
        f32x2 o = {v0, v1};
        ((f32x2*)out)[(size_t)d * 16 + lane] = o;
    } else {
        ((u32*)out)[(size_t)d * 16 + lane] = (u32)f2bf(v0) | ((u32)f2bf(v1) << 16);
    }
}

extern "C" void kernel_launch(void* const* d_in, const int* in_sizes, int n_in,
                              void* d_out, int out_size, void* d_ws, size_t ws_size,
                              hipStream_t stream) {
    const void* features = d_in[0];
    const int* src = (const int*)d_in[1];
    const int* dst = (const int*)d_in[2];

    char* ws = (char*)d_ws;
    size_t off = 0;
    auto carve = [&](size_t bytes) -> void* {
        void* p = ws + off;
        off = (off + bytes + 255) & ~(size_t)255;
        return p;
    };
    int*   flags = (int*)carve(64);
    float* pconv = (float*)carve(2048 * 4);
    u16*   Wp0 = (u16*)carve(65536 * 2);
    u16*   Wp1 = (u16*)carve(65536 * 2);
    u16*   Wp2 = (u16*)carve(8192 * 2);
    u16*   Xb    = (u16*)carve((size_t)NN * 256 * 2);  // bf16 hidden state
    u16*   featb = (u16*)carve((size_t)NN * 256 * 2);  // bf16 GEMM output
    float* el   = (float*)carve((size_t)NN * 8 * 4);
    float* er   = (float*)carve((size_t)NN * 8 * 4);
    int*   deg     = (int*)carve((size_t)NN * 4);
    int*   cursor  = (int*)carve((size_t)NN * 4);
    int*   rowptr  = (int*)carve((size_t)(NN + 1) * 4);
    int*   bsum    = (int*)carve(256 * 4);
    int*   csr_src = (int*)carve((size_t)NE * 4);
    if (off > ws_size) return;  // clean ws-too-small signature

    const int N = NN, E = NE;
    const int nscan = (N + 255) / 256;   // 196 <= 256

    // ---- merged prep: detect + convert + wpack x3 + deg-zero, ONE launch ----
    PrepArgs pa;
    const int din_idx[13] = {0, 3, 4, 5, 6, 7, 8, 9, 10, 11, 12, 13, 14};
    for (int j = 0; j < 13; ++j) {
        pa.dp[j] = (const u32*)d_in[din_idx[j]];
        int nw = in_sizes[din_idx[j]] / 2;
        pa.dnw[j] = nw > 512 ? 512 : nw;
    }
    const int psl[9] = {4, 5, 6, 8, 9, 10, 12, 13, 14};
    float* dsts[9];
    {
        size_t o = 0;
        for (int j = 0; j < 9; ++j) {
            dsts[j] = pconv + o;
            o += (size_t)in_sizes[psl[j]];
        }
    }
    for (int j = 0; j < 9; ++j) {
        pa.cs[j] = d_in[psl[j]];
        pa.cd[j] = dsts[j];
        pa.cn[j] = in_sizes[psl[j]];
    }
    pa.wsrc[0] = d_in[3];  pa.wdst[0] = Wp0; pa.wN[0] = 256; pa.wchunks[0] = 8192;
    pa.wsrc[1] = d_in[7];  pa.wdst[1] = Wp1; pa.wN[1] = 256; pa.wchunks[1] = 8192;
    pa.wsrc[2] = d_in[11]; pa.wdst[2] = Wp2; pa.wN[2] = 32;  pa.wchunks[2] = 1024;
    pa.deg = deg; pa.degn = N;
    k_prep<<<90 + nscan, 256, 0, stream>>>(pa, flags);
    float* al0f = dsts[0]; float* ar0f = dsts[1]; float* b0f = dsts[2];
    float* al1f = dsts[3]; float* ar1f = dsts[4]; float* b1f = dsts[5];
    float* al2f = dsts[6]; float* ar2f = dsts[7]; float* b2f = dsts[8];

    // CSR build (multi-block scan)
    k_hist<<<(E + 255) / 256, 256, 0, stream>>>(dst, deg, E);
    k_scan_partial<<<nscan, 256, 0, stream>>>(deg, bsum, N);
    k_scan_bsum<<<1, 256, 0, stream>>>(bsum, nscan);
    k_scan_final<<<nscan, 256, 0, stream>>>(deg, bsum, rowptr, cursor, N);
    k_scatter<<<(E + 255) / 256, 256, 0, stream>>>(src, dst, cursor, csr_src, E);

    const int ggrid = (N + 63) / 64;   // full-width gemm: 512 threads/block

    // ---------------- layer 0 (reads features directly, dtype via flag) ----
    k_gemm_mfma<<<ggrid, 512, 0, stream>>>(features, flags, Wp0, featb, N);
    k_elr8<<<(N * 8 + 255) / 256, 256, 0, stream>>>(featb, al0f, ar0f, el, er, N);
    k_gather8<<<N / 4, 256, 0, stream>>>(rowptr, csr_src, el, er,
                                         (const u32v2*)featb, b0f, (u32v2*)Xb);

    // ---------------- layer 1 ----------------
    k_gemm_mfma<<<ggrid, 512, 0, stream>>>(Xb, nullptr, Wp1, featb, N);
    k_elr8<<<(N * 8 + 255) / 256, 256, 0, stream>>>(featb, al1f, ar1f, el, er, N);
    k_gather8<<<N / 4, 256, 0, stream>>>(rowptr, csr_src, el, er,
                                         (const u32v2*)featb, b1f, (u32v2*)Xb);

    // ---------------- layer 2 (1 head, D=32) ----------------
    k_gemm_mfma32<<<(N + 127) / 128, 256, 0, stream>>>(Xb, Wp2, featb, N);
    k_elr1<<<(N + 255) / 256, 256, 0, stream>>>(featb, al2f, ar2f, el, er, N);
    k_gather1<<<(N + 15) / 16, 256, 0, stream>>>(rowptr, csr_src, el, er,
                                                 (const u32*)featb, b2f,
                                                 d_out, flags, N);
}

// Round 11
// 405.865 us; speedup vs baseline: 1.0386x; 1.0386x over previous
//
#include <hip/hip_runtime.h>

typedef unsigned short u16;
typedef unsigned int   u32;
typedef __attribute__((ext_vector_type(8))) short  short8;
typedef __attribute__((ext_vector_type(4))) float  f32x4;
typedef __attribute__((ext_vector_type(2))) float  f32x2;
typedef __attribute__((ext_vector_type(2))) unsigned int u32v2;
typedef __attribute__((ext_vector_type(4))) unsigned int u32v4;

#define NN 50000
#define NE 800000

__device__ __forceinline__ float bf2f(u16 b) { return __uint_as_float(((u32)b) << 16); }
__device__ __forceinline__ float bflo(u32 p) { return __uint_as_float(p << 16); }
__device__ __forceinline__ float bfhi(u32 p) { return __uint_as_float(p & 0xffff0000u); }
__device__ __forceinline__ u16 f2bf(float f) {
    u32 u = __float_as_uint(f);
    u32 r = u + 0x7fffu + ((u >> 16) & 1u);
    return (u16)(r >> 16);
}
// leaky-relu + clamped exp (clamp is identity for this data's logit range)
__device__ __forceinline__ float lexp(float v) {
    v = fmaxf(v, 0.2f * v);
    return __expf(fminf(v, 60.f));
}

// block-wide dtype detect (0=bf16, 1=fp32, 2=all-zero) from a 512-word
// prefix; result valid in ALL threads (reduction ends with syncthreads).
__device__ __forceinline__ int block_detect(const u32* x, int n, int* sh, int* sz) {
    int t = threadIdx.x;
    int hits = 0, nz = 0;
    for (int i = t; i < n; i += 256) {
        u32 w = x[i];
        if (w) {
            ++nz;
            u32 e = (w >> 7) & 0xffu;
            if (e >= 100 && e <= 150) ++hits;
        }
    }
    sh[t] = hits; sz[t] = nz;
    __syncthreads();
    for (int ofs = 128; ofs > 0; ofs >>= 1) {
        if (t < ofs) { sh[t] += sh[t + ofs]; sz[t] += sz[t + ofs]; }
        __syncthreads();
    }
    return (sz[0] == 0) ? 2 : ((sh[0] * 2 >= sz[0]) ? 0 : 1);
}

// ---------------------------------------------------------------------------
// k_prep: detect(13) + convert(9) + wpack x3 + deg-zeroing, ONE launch.
// ---------------------------------------------------------------------------
struct PrepArgs {
    const u32* dp[13]; int dnw[13];                 // detect
    const void* cs[9]; float* cd[9]; int cn[9];     // convert (n <= 256)
    const void* wsrc[3]; u16* wdst[3]; int wN[3]; int wchunks[3];  // wpack
    int* deg; int degn;                             // deg zeroing
};

__global__ __launch_bounds__(256) void k_prep(PrepArgs a, int* flags) {
    __shared__ int sh[256], sz[256];
    const int bid = blockIdx.x;
    const int t = threadIdx.x;
    if (bid < 13) {
        int f = block_detect(a.dp[bid], a.dnw[bid], sh, sz);
        if (t == 0) flags[bid] = f;
    } else if (bid < 22) {
        const int j = bid - 13;
        int nw = a.cn[j] / 2; if (nw > 512) nw = 512;
        const int fl = block_detect((const u32*)a.cs[j], nw, sh, sz);
        if (t < a.cn[j]) {
            float v = 0.f;
            if (fl == 1) v = ((const float*)a.cs[j])[t];
            else if (fl == 0) v = bf2f(((const u16*)a.cs[j])[t]);
            a.cd[j][t] = v;
        }
    } else if (bid < 90) {
        int wj, base;
        if (bid < 54)      { wj = 0; base = 22; }
        else if (bid < 86) { wj = 1; base = 54; }
        else               { wj = 2; base = 86; }
        const void* Wsrc = a.wsrc[wj];
        const int fl = block_detect((const u32*)Wsrc, 512, sh, sz);
        const int id = (bid - base) * 256 + t;
        if (id < a.wchunks[wj]) {
            const int L = id & 63, kt = (id >> 6) & 7, nt = id >> 9;
            const int col = nt * 16 + (L & 15);
            const int krow = kt * 32 + ((L >> 4) & 3) * 8;
            const bool isf32 = (fl == 1);
            const int N = a.wN[wj];
            u16* Wp = a.wdst[wj];
#pragma unroll
            for (int j2 = 0; j2 < 8; ++j2) {
                int s = (krow + j2) * N + col;
                Wp[id * 8 + j2] = isf32 ? f2bf(((const float*)Wsrc)[s])
                                        : ((const u16*)Wsrc)[s];
            }
        }
    } else {
        const int i = (bid - 90) * 256 + t;
        if (i < a.degn) a.deg[i] = 0;
    }
}

// ---------------------------------------------------------------------------
// k_fA (r11): FULL-WIDTH GEMM L0 + histogram, one launch (independent work:
// gemm is MFMA/LDS-bound, hist is random-atomic-bound -> concurrent blocks
// use disjoint pipes; hipEvent* is banned so blockIdx-split fusion is the
// only legal concurrency). Blocks [0,gb): gemm; [gb, gb+1563): hist.
// ---------------------------------------------------------------------------
__global__ __launch_bounds__(512) void k_fA(const void* __restrict__ Xv,
                                            const int* __restrict__ xflag,
                                            const u16* __restrict__ Wp,
                                            u16* __restrict__ OUT, int nrows,
                                            const int* __restrict__ dstv,
                                            int* __restrict__ deg, int E) {
    __shared__ u16 As[64 * 256];   // 32 KB
    const int gblocks = (nrows + 63) >> 6;
    if ((int)blockIdx.x >= gblocks) {
        const int e = (blockIdx.x - gblocks) * 512 + threadIdx.x;
        if (e < E) atomicAdd(&deg[dstv[e]], 1);
        return;
    }
    const int t = threadIdx.x;
    const int w = t >> 6, L = t & 63;
    const int quad = (L >> 4) & 3;
    const int r0 = blockIdx.x * 64;
    const bool xf32 = (xflag != nullptr) && (*xflag == 1);

    short8* Asv = (short8*)As;
    short8 zero = {0, 0, 0, 0, 0, 0, 0, 0};
#pragma unroll
    for (int i = 0; i < 4; ++i) {
        int g = i * 512 + t;
        int row = g >> 5, cc = g & 31;
        int r = r0 + row;
        short8 val = zero;
        if (r < nrows) {
            if (xf32) {
                const f32x4* Xf4 = (const f32x4*)Xv;
                f32x4 lo = Xf4[(size_t)r * 64 + cc * 2];
                f32x4 hi = Xf4[(size_t)r * 64 + cc * 2 + 1];
                val[0] = (short)f2bf(lo[0]); val[1] = (short)f2bf(lo[1]);
                val[2] = (short)f2bf(lo[2]); val[3] = (short)f2bf(lo[3]);
                val[4] = (short)f2bf(hi[0]); val[5] = (short)f2bf(hi[1]);
                val[6] = (short)f2bf(hi[2]); val[7] = (short)f2bf(hi[3]);
            } else {
                val = ((const short8*)Xv)[(size_t)r * 32 + cc];
            }
        }
        Asv[cc * 64 + (row ^ (cc & 7))] = val;
    }

    const short8* Wv = (const short8*)Wp;
    short8 bf[2][8];
#pragma unroll
    for (int jn = 0; jn < 2; ++jn) {
        int nt = w + jn * 8;
#pragma unroll
        for (int kt = 0; kt < 8; ++kt) bf[jn][kt] = Wv[(nt * 8 + kt) * 64 + L];
    }
    __syncthreads();

    f32x4 acc[4][2];
#pragma unroll
    for (int mi = 0; mi < 4; ++mi)
#pragma unroll
        for (int jn = 0; jn < 2; ++jn) acc[mi][jn] = (f32x4){0.f, 0.f, 0.f, 0.f};

#pragma unroll
    for (int kt = 0; kt < 8; ++kt) {
        const int ccr = kt * 4 + quad;
#pragma unroll
        for (int mi = 0; mi < 4; ++mi) {
            short8 af = Asv[ccr * 64 + ((mi * 16 + (L & 15)) ^ (ccr & 7))];
            acc[mi][0] = __builtin_amdgcn_mfma_f32_16x16x32_bf16(af, bf[0][kt], acc[mi][0], 0, 0, 0);
            acc[mi][1] = __builtin_amdgcn_mfma_f32_16x16x32_bf16(af, bf[1][kt], acc[mi][1], 0, 0, 0);
        }
    }

#pragma unroll
    for (int mi = 0; mi < 4; ++mi) {
        int rb = r0 + mi * 16 + quad * 4;
#pragma unroll
        for (int jn = 0; jn < 2; ++jn) {
            int c = (w + jn * 8) * 16 + (L & 15);
#pragma unroll
            for (int reg = 0; reg < 4; ++reg) {
                int r = rb + reg;
                if (r < nrows) OUT[(size_t)r * 256 + c] = f2bf(acc[mi][jn][reg]);
            }
        }
    }
}

// ---------------------------------------------------------------------------
// scan: partial sums, then final (final re-scans the 196 partials in LDS
// itself -> the separate bsum launch is gone, r11).
// ---------------------------------------------------------------------------
__global__ __launch_bounds__(256) void k_scan_partial(const int* __restrict__ deg,
                                                      int* __restrict__ bsum, int n) {
    __shared__ int red[256];
    int t = threadIdx.x;
    int i = blockIdx.x * 256 + t;
    red[t] = (i < n) ? deg[i] : 0;
    __syncthreads();
    for (int ofs = 128; ofs > 0; ofs >>= 1) {
        if (t < ofs) red[t] += red[t + ofs];
        __syncthreads();
    }
    if (t == 0) bsum[blockIdx.x] = red[0];
}

__global__ __launch_bounds__(256) void k_scan_final(const int* __restrict__ deg,
                                                    const int* __restrict__ bsum,
                                                    int* __restrict__ rowptr,
                                                    int* __restrict__ cursor,
                                                    int n, int nb) {
    __shared__ int s[256], bs[256];
    int t = threadIdx.x;
    // local scan of the per-block partials (replaces k_scan_bsum)
    bs[t] = (t < nb) ? bsum[t] : 0;
    __syncthreads();
    for (int ofs = 1; ofs < 256; ofs <<= 1) {
        int x = (t >= ofs) ? bs[t - ofs] : 0;
        __syncthreads();
        bs[t] += x;
        __syncthreads();
    }
    const int bexcl = (blockIdx.x == 0) ? 0 : bs[blockIdx.x - 1];

    int i = blockIdx.x * 256 + t;
    int v = (i < n) ? deg[i] : 0;
    s[t] = v;
    __syncthreads();
    for (int ofs = 1; ofs < 256; ofs <<= 1) {
        int x = (t >= ofs) ? s[t - ofs] : 0;
        __syncthreads();
        s[t] += x;
        __syncthreads();
    }
    int excl = bexcl + s[t] - v;
    if (i < n) {
        rowptr[i] = excl;
        cursor[i] = excl;
        if (i == n - 1) rowptr[n] = excl + v;
    }
}

// ---------------------------------------------------------------------------
// k_fB (r11): scatter + elr8(L0), one launch (independent: scatter is
// atomic/scatter-write-bound, elr8 is streaming-read-bound).
// Blocks [0,3125): scatter; rest: elr8.
// ---------------------------------------------------------------------------
__global__ __launch_bounds__(256) void k_fB(const int* __restrict__ src,
                                            const int* __restrict__ dstv,
                                            int* __restrict__ cursor,
                                            int* __restrict__ csr_src, int E,
                                            const u16* __restrict__ featb,
                                            const float* __restrict__ al,
                                            const float* __restrict__ ar,
                                            float* __restrict__ el,
                                            float* __restrict__ er, int n) {
    const int nsc = (E + 255) >> 8;
    if ((int)blockIdx.x < nsc) {
        const int e = blockIdx.x * 256 + threadIdx.x;
        if (e < E) {
            int p = atomicAdd(&cursor[dstv[e]], 1);
            csr_src[p] = src[e];
        }
        return;
    }
    const int idx = (blockIdx.x - nsc) * 256 + threadIdx.x;
    if (idx >= n * 8) return;
    const int node = idx >> 3, h = idx & 7;
    const u32v4* fu = (const u32v4*)((const u32*)featb + (size_t)node * 128 + h * 16);
    const float* A = al + h * 32;
    const float* B = ar + h * 32;
    float sl = 0.f, sr = 0.f;
#pragma unroll
    for (int j = 0; j < 4; ++j) {
        u32v4 w4 = fu[j];
#pragma unroll
        for (int k = 0; k < 4; ++k) {
            u32 w = (k == 0) ? w4.x : (k == 1) ? w4.y : (k == 2) ? w4.z : w4.w;
            float f0 = bflo(w), f1 = bfhi(w);
            int c = j * 8 + k * 2;
            sl += f0 * A[c] + f1 * A[c + 1];
            sr += f0 * B[c] + f1 * B[c + 1];
        }
    }
    el[idx] = sl;
    er[idx] = sr;
}

// ---------------------------------------------------------------------------
// MFMA GEMM (FULL-WIDTH, r9): standalone for layer 1 (no concurrent work
// available there). X staged ONCE; As XOR-swizzled.
// ---------------------------------------------------------------------------
__global__ __launch_bounds__(512) void k_gemm_mfma(const void* __restrict__ Xv,
                                                   const int* __restrict__ xflag,
                                                   const u16* __restrict__ Wp,
                                                   u16* __restrict__ OUT, int nrows) {
    __shared__ u16 As[64 * 256];   // 32 KB
    const int t = threadIdx.x;
    const int w = t >> 6, L = t & 63;
    const int quad = (L >> 4) & 3;
    const int r0 = blockIdx.x * 64;
    const bool xf32 = (xflag != nullptr) && (*xflag == 1);

    short8* Asv = (short8*)As;
    short8 zero = {0, 0, 0, 0, 0, 0, 0, 0};
#pragma unroll
    for (int i = 0; i < 4; ++i) {
        int g = i * 512 + t;
        int row = g >> 5, cc = g & 31;
        int r = r0 + row;
        short8 val = zero;
        if (r < nrows) {
            if (xf32) {
                const f32x4* Xf4 = (const f32x4*)Xv;
                f32x4 lo = Xf4[(size_t)r * 64 + cc * 2];
                f32x4 hi = Xf4[(size_t)r * 64 + cc * 2 + 1];
                val[0] = (short)f2bf(lo[0]); val[1] = (short)f2bf(lo[1]);
                val[2] = (short)f2bf(lo[2]); val[3] = (short)f2bf(lo[3]);
                val[4] = (short)f2bf(hi[0]); val[5] = (short)f2bf(hi[1]);
                val[6] = (short)f2bf(hi[2]); val[7] = (short)f2bf(hi[3]);
            } else {
                val = ((const short8*)Xv)[(size_t)r * 32 + cc];
            }
        }
        Asv[cc * 64 + (row ^ (cc & 7))] = val;
    }

    const short8* Wv = (const short8*)Wp;
    short8 bf[2][8];
#pragma unroll
    for (int jn = 0; jn < 2; ++jn) {
        int nt = w + jn * 8;
#pragma unroll
        for (int kt = 0; kt < 8; ++kt) bf[jn][kt] = Wv[(nt * 8 + kt) * 64 + L];
    }
    __syncthreads();

    f32x4 acc[4][2];
#pragma unroll
    for (int mi = 0; mi < 4; ++mi)
#pragma unroll
        for (int jn = 0; jn < 2; ++jn) acc[mi][jn] = (f32x4){0.f, 0.f, 0.f, 0.f};

#pragma unroll
    for (int kt = 0; kt < 8; ++kt) {
        const int ccr = kt * 4 + quad;
#pragma unroll
        for (int mi = 0; mi < 4; ++mi) {
            short8 af = Asv[ccr * 64 + ((mi * 16 + (L & 15)) ^ (ccr & 7))];
            acc[mi][0] = __builtin_amdgcn_mfma_f32_16x16x32_bf16(af, bf[0][kt], acc[mi][0], 0, 0, 0);
            acc[mi][1] = __builtin_amdgcn_mfma_f32_16x16x32_bf16(af, bf[1][kt], acc[mi][1], 0, 0, 0);
        }
    }

#pragma unroll
    for (int mi = 0; mi < 4; ++mi) {
        int rb = r0 + mi * 16 + quad * 4;
#pragma unroll
        for (int jn = 0; jn < 2; ++jn) {
            int c = (w + jn * 8) * 16 + (L & 15);
#pragma unroll
            for (int reg = 0; reg < 4; ++reg) {
                int r = rb + reg;
                if (r < nrows) OUT[(size_t)r * 256 + c] = f2bf(acc[mi][jn][reg]);
            }
        }
    }
}

// MFMA GEMM layer 2: [nrows,256](bf16) x Wp2 -> bf16 [nrows,32]. BM=128, BN=32.
__global__ __launch_bounds__(256) void k_gemm_mfma32(const u16* __restrict__ Xb,
                                                     const u16* __restrict__ Wp,
                                                     u16* __restrict__ OUT, int nrows) {
    __shared__ u16 As[128 * 256];  // 64 KB
    const int t = threadIdx.x;
    const int w = t >> 6, L = t & 63;
    const int quad = (L >> 4) & 3;
    const int r0 = blockIdx.x * 128;
    const int mh = (w >> 1) * 64, nt = w & 1;

    const short8* Xv = (const short8*)Xb;
    short8* Asv = (short8*)As;
    short8 zero = {0, 0, 0, 0, 0, 0, 0, 0};
#pragma unroll
    for (int i = 0; i < 16; ++i) {
        int g = i * 256 + t;
        int row = g >> 5, cc = g & 31;
        int r = r0 + row;
        Asv[cc * 128 + (row ^ (cc & 7))] = (r < nrows) ? Xv[(size_t)r * 32 + cc] : zero;
    }

    const short8* Wv = (const short8*)Wp;
    short8 bf[8];
#pragma unroll
    for (int kt = 0; kt < 8; ++kt) bf[kt] = Wv[(nt * 8 + kt) * 64 + L];
    __syncthreads();

    f32x4 acc[4];
#pragma unroll
    for (int mi = 0; mi < 4; ++mi) acc[mi] = (f32x4){0.f, 0.f, 0.f, 0.f};

#pragma unroll
    for (int kt = 0; kt < 8; ++kt) {
        const int ccr = kt * 4 + quad;
#pragma unroll
        for (int mi = 0; mi < 4; ++mi) {
            short8 af = Asv[ccr * 128 + ((mh + mi * 16 + (L & 15)) ^ (ccr & 7))];
            acc[mi] = __builtin_amdgcn_mfma_f32_16x16x32_bf16(af, bf[kt], acc[mi], 0, 0, 0);
        }
    }

#pragma unroll
    for (int mi = 0; mi < 4; ++mi) {
        int rb = r0 + mh + mi * 16 + quad * 4;
        int c = nt * 16 + (L & 15);
#pragma unroll
        for (int reg = 0; reg < 4; ++reg) {
            int r = rb + reg;
            if (r < nrows) OUT[(size_t)r * 32 + c] = f2bf(acc[mi][reg]);
        }
    }
}

// attention logit dots (feat bf16 node-major, dwordx4 loads) — layer 1
__global__ void k_elr8(const u16* __restrict__ featb, const float* __restrict__ al,
                       const float* __restrict__ ar, float* __restrict__ el,
                       float* __restrict__ er, int n) {
    int idx = blockIdx.x * 256 + threadIdx.x;
    if (idx >= n * 8) return;
    int node = idx >> 3, h = idx & 7;
    const u32v4* fu = (const u32v4*)((const u32*)featb + (size_t)node * 128 + h * 16);
    const float* A = al + h * 32;
    const float* B = ar + h * 32;
    float sl = 0.f, sr = 0.f;
#pragma unroll
    for (int j = 0; j < 4; ++j) {
        u32v4 w4 = fu[j];
#pragma unroll
        for (int k = 0; k < 4; ++k) {
            u32 w = (k == 0) ? w4.x : (k == 1) ? w4.y : (k == 2) ? w4.z : w4.w;
            float f0 = bflo(w), f1 = bfhi(w);
            int c = j * 8 + k * 2;
            sl += f0 * A[c] + f1 * A[c + 1];
            sr += f0 * B[c] + f1 * B[c + 1];
        }
    }
    el[idx] = sl;
    er[idx] = sr;
}

__global__ void k_elr1(const u16* __restrict__ featb, const float* __restrict__ al,
                       const float* __restrict__ ar, float* __restrict__ el,
                       float* __restrict__ er, int n) {
    int node = blockIdx.x * 256 + threadIdx.x;
    if (node >= n) return;
    const u32v4* fu = (const u32v4*)((const u32*)featb + (size_t)node * 16);
    float sl = 0.f, sr = 0.f;
#pragma unroll
    for (int j = 0; j < 4; ++j) {
        u32v4 w4 = fu[j];
#pragma unroll
        for (int k = 0; k < 4; ++k) {
            u32 w = (k == 0) ? w4.x : (k == 1) ? w4.y : (k == 2) ? w4.z : w4.w;
            float f0 = bflo(w), f1 = bfhi(w);
            int c = j * 8 + k * 2;
            sl += f0 * al[c] + f1 * al[c + 1];
            sr += f0 * ar[c] + f1 * ar[c + 1];
        }
    }
    el[node] = sl;
    er[node] = sr;
}

// ---------------------------------------------------------------------------
// fused softmax+gather: ONE WAVE PER NODE (64 lanes x dwordx2 = 4 cols/lane),
// software-pipelined 8-edge chunks (MEASURED-BEST, six rounds stable:
// 65.5us @ 209MB / 3.67TB/s = the random-512B-chunk L3->L2 fill ceiling).
// ---------------------------------------------------------------------------
__global__ __launch_bounds__(256) void k_gather8(const int* __restrict__ rowptr,
                                                 const int* __restrict__ csr_src,
                                                 const float* __restrict__ el,
                                                 const float* __restrict__ er,
                                                 const u32v2* __restrict__ featb4,
                                                 const float* __restrict__ bias,
                                                 u32v2* __restrict__ xout4) {
    __shared__ __align__(16) float sAL[4][2][64];   // [wave][buf][h*8+e]
    __shared__ __align__(16) int   sSL[4][2][8];    // [wave][buf][e]
    const int t = threadIdx.x;
    const int wv = t >> 6;
    const int q = t & 63;            // owns cols 4q..4q+3, head h = q>>3
    const int d = blockIdx.x * 4 + wv;
    const int eL = q >> 3, hL = q & 7;   // producer role: edge eL, head hL
    const int b = rowptr[d], e = rowptr[d + 1];
    const int deg = e - b;
    const int nch = (deg + 7) >> 3;
    const float erA = er[d * 8 + hL];

    float (*AL)[64] = sAL[wv];
    int (*SL)[8] = sSL[wv];

    float a0 = 0.f, a1 = 0.f, a2 = 0.f, a3 = 0.f;
    float partial = 0.f;

    u32v2 fw[8], fw2[8];
    int csrP = 0, ncP = 0;
    float elP = 0.f;

    if (nch > 0) {
        // prologue: stage chunk 0 fully; issue chunk-1 csr + el
        const int nc0 = deg < 8 ? deg : 8;
        const int i0 = eL < nc0 ? eL : nc0 - 1;
        const int s0 = csr_src[b + i0];
        if (nch > 1) {
            const int r1 = deg - 8;
            ncP = r1 < 8 ? r1 : 8;
            const int i1 = eL < ncP ? eL : ncP - 1;
            csrP = csr_src[b + 8 + i1];
        }
        const float el0 = el[s0 * 8 + hL];
        if (hL == 0) SL[0][eL] = s0;
        const int4 sv0 = *(const int4*)&SL[0][0];
        const int4 sv1 = *(const int4*)&SL[0][4];
        fw[0] = featb4[sv0.x * 64 + q];
        fw[1] = featb4[sv0.y * 64 + q];
        fw[2] = featb4[sv0.z * 64 + q];
        fw[3] = featb4[sv0.w * 64 + q];
        fw[4] = featb4[sv1.x * 64 + q];
        fw[5] = featb4[sv1.y * 64 + q];
        fw[6] = featb4[sv1.z * 64 + q];
        fw[7] = featb4[sv1.w * 64 + q];
        const float ex0 = (eL < nc0) ? lexp(el0 + erA) : 0.f;
        partial += ex0;
        AL[0][hL * 8 + eL] = ex0;
        if (nch > 1) elP = el[csrP * 8 + hL];
    }

    for (int c = 0; c < nch; ++c) {
        const int cur = c & 1, nxt = cur ^ 1;

        // issue csr for chunk c+2 (2-deep so c+1's el issue never stalls)
        int csrF = 0, ncF = 0;
        if (c + 2 < nch) {
            const int r2 = deg - (c + 2) * 8;
            ncF = r2 < 8 ? r2 : 8;
            const int i2 = eL < ncF ? eL : ncF - 1;
            csrF = csr_src[b + (c + 2) * 8 + i2];
        }

        // stage chunk c+1: s-list -> LDS -> feat issues; alpha -> LDS
        if (c + 1 < nch) {
            if (hL == 0) SL[nxt][eL] = csrP;
            const int4 sv0 = *(const int4*)&SL[nxt][0];
            const int4 sv1 = *(const int4*)&SL[nxt][4];
            fw2[0] = featb4[sv0.x * 64 + q];
            fw2[1] = featb4[sv0.y * 64 + q];
            fw2[2] = featb4[sv0.z * 64 + q];
            fw2[3] = featb4[sv0.w * 64 + q];
            fw2[4] = featb4[sv1.x * 64 + q];
            fw2[5] = featb4[sv1.y * 64 + q];
            fw2[6] = featb4[sv1.z * 64 + q];
            fw2[7] = featb4[sv1.w * 64 + q];
            const float exN = (eL < ncP) ? lexp(elP + erA) : 0.f;
            partial += exN;
            AL[nxt][hL * 8 + eL] = exN;
        }

        // read alpha chunk c (broadcast ds_read_b128 x2, conflict-free)
        const int h8 = (q >> 3) * 8;
        const f32x4 A0 = *(const f32x4*)&AL[cur][h8];
        const f32x4 A1 = *(const f32x4*)&AL[cur][h8 + 4];

        // issue el for chunk c+2 (elP consumed above; safe to overwrite)
        if (c + 2 < nch) elP = el[csrF * 8 + hL];

        // FMA chunk c (feat issued one full chunk ago -> latency hidden)
#define GAT_EDGE(i, axv) { const u32v2 w_ = fw[i]; \
        a0 += bflo(w_.x) * (axv); a1 += bfhi(w_.x) * (axv); \
        a2 += bflo(w_.y) * (axv); a3 += bfhi(w_.y) * (axv); }
        GAT_EDGE(0, A0[0]) GAT_EDGE(1, A0[1]) GAT_EDGE(2, A0[2]) GAT_EDGE(3, A0[3])
        GAT_EDGE(4, A1[0]) GAT_EDGE(5, A1[1]) GAT_EDGE(6, A1[2]) GAT_EDGE(7, A1[3])
#undef GAT_EDGE

        // rotate pipeline state
#pragma unroll
        for (int i = 0; i < 8; ++i) fw[i] = fw2[i];
        csrP = csrF;
        ncP = ncF;
    }

    // denominator: reduce producer partials across eL (bits 3..5), then
    // fetch the consumer head's sum from lane (q>>3)
    float v = partial;
    v += __shfl_xor(v, 8);
    v += __shfl_xor(v, 16);
    v += __shfl_xor(v, 32);
    const float ssd = __shfl(v, q >> 3);

    const float rd = 1.f / (ssd + 1e-9f);
    const float4 bb = *(const float4*)&bias[4 * q];
    float v0 = a0 * rd + bb.x;
    float v1 = a1 * rd + bb.y;
    float v2 = a2 * rd + bb.z;
    float v3 = a3 * rd + bb.w;
    v0 = v0 > 0.f ? v0 : expm1f(v0);
    v1 = v1 > 0.f ? v1 : expm1f(v1);
    v2 = v2 > 0.f ? v2 : expm1f(v2);
    v3 = v3 > 0.f ? v3 : expm1f(v3);
    u32v2 o;
    o.x = (u32)f2bf(v0) | ((u32)f2bf(v1) << 16);
    o.y = (u32)f2bf(v2) | ((u32)f2bf(v3) << 16);
    xout4[(size_t)d * 64 + q] = o;
}

// layer-2 fused gather (r10 pipelined form, kept: no regression, cleaner).
__global__ __launch_bounds__(256) void k_gather1(const int* __restrict__ rowptr,
                                                 const int* __restrict__ csr_src,
                                                 const float* __restrict__ el,
                                                 const float* __restrict__ er,
                                                 const u32* __restrict__ featb2,
                                                 const float* __restrict__ bias,
                                                 void* __restrict__ out,
                                                 const int* __restrict__ flag, int n) {
    const int t = threadIdx.x;
    const int d = blockIdx.x * 16 + (t >> 4);
    const int lane = t & 15;          // owns cols 2*lane, 2*lane+1
    if (d >= n) return;
    const int b = rowptr[d], e = rowptr[d + 1];
    const float erd = er[d];
    float a0 = 0.f, a1 = 0.f, ssum = 0.f;

    for (int c = b; c < e; c += 16) {
        const int idx = c + lane;
        const int s_own = csr_src[idx < e ? idx : e - 1];
        const float ex_own = (idx < e) ? lexp(el[s_own] + erd) : 0.f;
        ssum += ex_own;
#pragma unroll
        for (int i = 0; i < 16; ++i) {
            const int si = __shfl(s_own, i, 16);
            const float ai = __shfl(ex_own, i, 16);
            const u32 w = featb2[(size_t)si * 16 + lane];
            a0 += bflo(w) * ai;
            a1 += bfhi(w) * ai;
        }
    }

    ssum += __shfl_xor(ssum, 1);
    ssum += __shfl_xor(ssum, 2);
    ssum += __shfl_xor(ssum, 4);
    ssum += __shfl_xor(ssum, 8);

    const float rd = 1.f / (ssum + 1e-9f);
    const float v0 = a0 * rd + bias[2 * lane];
    const float v1 = a1 * rd + bias[2 * lane + 1];
    if (*flag == 1) {
        f32x2 o = {v0, v1};
        ((f32x2*)out)[(size_t)d * 16 + lane] = o;
    } else {
        ((u32*)out)[(size_t)d * 16 + lane] = (u32)f2bf(v0) | ((u32)f2bf(v1) << 16);
    }
}

extern "C" void kernel_launch(void* const* d_in, const int* in_sizes, int n_in,
                              void* d_out, int out_size, void* d_ws, size_t ws_size,
                              hipStream_t stream) {
    const void* features = d_in[0];
    const int* src = (const int*)d_in[1];
    const int* dst = (const int*)d_in[2];

    char* ws = (char*)d_ws;
    size_t off = 0;
    auto carve = [&](size_t bytes) -> void* {
        void* p = ws + off;
        off = (off + bytes + 255) & ~(size_t)255;
        return p;
    };
    int*   flags = (int*)carve(64);
    float* pconv = (float*)carve(2048 * 4);
    u16*   Wp0 = (u16*)carve(65536 * 2);
    u16*   Wp1 = (u16*)carve(65536 * 2);
    u16*   Wp2 = (u16*)carve(8192 * 2);
    u16*   Xb    = (u16*)carve((size_t)NN * 256 * 2);  // bf16 hidden state
    u16*   featb = (u16*)carve((size_t)NN * 256 * 2);  // bf16 GEMM output
    float* el   = (float*)carve((size_t)NN * 8 * 4);
    float* er   = (float*)carve((size_t)NN * 8 * 4);
    int*   deg     = (int*)carve((size_t)NN * 4);
    int*   cursor  = (int*)carve((size_t)NN * 4);
    int*   rowptr  = (int*)carve((size_t)(NN + 1) * 4);
    int*   bsum    = (int*)carve(256 * 4);
    int*   csr_src = (int*)carve((size_t)NE * 4);
    if (off > ws_size) return;  // clean ws-too-small signature

    const int N = NN, E = NE;
    const int nscan = (N + 255) / 256;   // 196 <= 256

    // ---- merged prep: detect + convert + wpack x3 + deg-zero, ONE launch ----
    PrepArgs pa;
    const int din_idx[13] = {0, 3, 4, 5, 6, 7, 8, 9, 10, 11, 12, 13, 14};
    for (int j = 0; j < 13; ++j) {
        pa.dp[j] = (const u32*)d_in[din_idx[j]];
        int nw = in_sizes[din_idx[j]] / 2;
        pa.dnw[j] = nw > 512 ? 512 : nw;
    }
    const int psl[9] = {4, 5, 6, 8, 9, 10, 12, 13, 14};
    float* dsts[9];
    {
        size_t o = 0;
        for (int j = 0; j < 9; ++j) {
            dsts[j] = pconv + o;
            o += (size_t)in_sizes[psl[j]];
        }
    }
    for (int j = 0; j < 9; ++j) {
        pa.cs[j] = d_in[psl[j]];
        pa.cd[j] = dsts[j];
        pa.cn[j] = in_sizes[psl[j]];
    }
    pa.wsrc[0] = d_in[3];  pa.wdst[0] = Wp0; pa.wN[0] = 256; pa.wchunks[0] = 8192;
    pa.wsrc[1] = d_in[7];  pa.wdst[1] = Wp1; pa.wN[1] = 256; pa.wchunks[1] = 8192;
    pa.wsrc[2] = d_in[11]; pa.wdst[2] = Wp2; pa.wN[2] = 32;  pa.wchunks[2] = 1024;
    pa.deg = deg; pa.degn = N;
    k_prep<<<90 + nscan, 256, 0, stream>>>(pa, flags);
    float* al0f = dsts[0]; float* ar0f = dsts[1]; float* b0f = dsts[2];
    float* al1f = dsts[3]; float* ar1f = dsts[4]; float* b1f = dsts[5];
    float* al2f = dsts[6]; float* ar2f = dsts[7]; float* b2f = dsts[8];

    const int ggrid = (N + 63) / 64;           // 782 gemm blocks
    const int hblocks = (E + 511) / 512;       // 1563 hist blocks

    // ---- layer 0 gemm + CSR hist, ONE launch (independent) ----
    k_fA<<<ggrid + hblocks, 512, 0, stream>>>(features, flags, Wp0, featb, N,
                                              dst, deg, E);

    // scan (partial -> final; bsum folded into final)
    k_scan_partial<<<nscan, 256, 0, stream>>>(deg, bsum, N);
    k_scan_final<<<nscan, 256, 0, stream>>>(deg, bsum, rowptr, cursor, N, nscan);

    // ---- scatter + elr8 L0, ONE launch (independent) ----
    const int scb = (E + 255) / 256;           // 3125 scatter blocks
    const int elb = (N * 8 + 255) / 256;       // 1563 elr8 blocks
    k_fB<<<scb + elb, 256, 0, stream>>>(src, dst, cursor, csr_src, E,
                                        featb, al0f, ar0f, el, er, N);

    k_gather8<<<N / 4, 256, 0, stream>>>(rowptr, csr_src, el, er,
                                         (const u32v2*)featb, b0f, (u32v2*)Xb);

    // ---------------- layer 1 ----------------
    k_gemm_mfma<<<ggrid, 512, 0, stream>>>(Xb, nullptr, Wp1, featb, N);
    k_elr8<<<elb, 256, 0, stream>>>(featb, al1f, ar1f, el, er, N);
    k_gather8<<<N / 4, 256, 0, stream>>>(rowptr, csr_src, el, er,
                                         (const u32v2*)featb, b1f, (u32v2*)Xb);

    // ---------------- layer 2 (1 head, D=32) ----------------
    k_gemm_mfma32<<<(N + 127) / 128, 256, 0, stream>>>(Xb, Wp2, featb, N);
    k_elr1<<<(N + 255) / 256, 256, 0, stream>>>(featb, al2f, ar2f, el, er, N);
    k_gather1<<<(N + 15) / 16, 256, 0, stream>>>(rowptr, csr_src, el, er,
                                                 (const u32*)featb, b2f,
                                                 d_out, flags, N);
}

// Round 12
// 399.500 us; speedup vs baseline: 1.0551x; 1.0159x over previous
//
#include <hip/hip_runtime.h>

typedef unsigned short u16;
typedef unsigned int   u32;
typedef __attribute__((ext_vector_type(8))) short  short8;
typedef __attribute__((ext_vector_type(4))) float  f32x4;
typedef __attribute__((ext_vector_type(2))) float  f32x2;
typedef __attribute__((ext_vector_type(2))) unsigned int u32v2;
typedef __attribute__((ext_vector_type(4))) unsigned int u32v4;

#define NN 50000
#define NE 800000
#define SLICE 6250   // NN/8 nodes per XCD slice

__device__ __forceinline__ float bf2f(u16 b) { return __uint_as_float(((u32)b) << 16); }
__device__ __forceinline__ float bflo(u32 p) { return __uint_as_float(p << 16); }
__device__ __forceinline__ float bfhi(u32 p) { return __uint_as_float(p & 0xffff0000u); }
__device__ __forceinline__ u16 f2bf(float f) {
    u32 u = __float_as_uint(f);
    u32 r = u + 0x7fffu + ((u >> 16) & 1u);
    return (u16)(r >> 16);
}
// leaky-relu + clamped exp (clamp is identity for this data's logit range)
__device__ __forceinline__ float lexp(float v) {
    v = fmaxf(v, 0.2f * v);
    return __expf(fminf(v, 60.f));
}

// block-wide dtype detect (0=bf16, 1=fp32, 2=all-zero) from a 512-word
// prefix; result valid in ALL threads (reduction ends with syncthreads).
__device__ __forceinline__ int block_detect(const u32* x, int n, int* sh, int* sz) {
    int t = threadIdx.x;
    int hits = 0, nz = 0;
    for (int i = t; i < n; i += 256) {
        u32 w = x[i];
        if (w) {
            ++nz;
            u32 e = (w >> 7) & 0xffu;
            if (e >= 100 && e <= 150) ++hits;
        }
    }
    sh[t] = hits; sz[t] = nz;
    __syncthreads();
    for (int ofs = 128; ofs > 0; ofs >>= 1) {
        if (t < ofs) { sh[t] += sh[t + ofs]; sz[t] += sz[t + ofs]; }
        __syncthreads();
    }
    return (sz[0] == 0) ? 2 : ((sh[0] * 2 >= sz[0]) ? 0 : 1);
}

// ---------------------------------------------------------------------------
// k_prep: detect(13) + convert(9) + wpack x3 + deg-zeroing, ONE launch.
// ---------------------------------------------------------------------------
struct PrepArgs {
    const u32* dp[13]; int dnw[13];                 // detect
    const void* cs[9]; float* cd[9]; int cn[9];     // convert (n <= 256)
    const void* wsrc[3]; u16* wdst[3]; int wN[3]; int wchunks[3];  // wpack
    int* deg; int degn;                             // deg zeroing
};

__global__ __launch_bounds__(256) void k_prep(PrepArgs a, int* flags) {
    __shared__ int sh[256], sz[256];
    const int bid = blockIdx.x;
    const int t = threadIdx.x;
    if (bid < 13) {
        int f = block_detect(a.dp[bid], a.dnw[bid], sh, sz);
        if (t == 0) flags[bid] = f;
    } else if (bid < 22) {
        const int j = bid - 13;
        int nw = a.cn[j] / 2; if (nw > 512) nw = 512;
        const int fl = block_detect((const u32*)a.cs[j], nw, sh, sz);
        if (t < a.cn[j]) {
            float v = 0.f;
            if (fl == 1) v = ((const float*)a.cs[j])[t];
            else if (fl == 0) v = bf2f(((const u16*)a.cs[j])[t]);
            a.cd[j][t] = v;
        }
    } else if (bid < 90) {
        int wj, base;
        if (bid < 54)      { wj = 0; base = 22; }
        else if (bid < 86) { wj = 1; base = 54; }
        else               { wj = 2; base = 86; }
        const void* Wsrc = a.wsrc[wj];
        const int fl = block_detect((const u32*)Wsrc, 512, sh, sz);
        const int id = (bid - base) * 256 + t;
        if (id < a.wchunks[wj]) {
            const int L = id & 63, kt = (id >> 6) & 7, nt = id >> 9;
            const int col = nt * 16 + (L & 15);
            const int krow = kt * 32 + ((L >> 4) & 3) * 8;
            const bool isf32 = (fl == 1);
            const int N = a.wN[wj];
            u16* Wp = a.wdst[wj];
#pragma unroll
            for (int j2 = 0; j2 < 8; ++j2) {
                int s = (krow + j2) * N + col;
                Wp[id * 8 + j2] = isf32 ? f2bf(((const float*)Wsrc)[s])
                                        : ((const u16*)Wsrc)[s];
            }
        }
    } else {
        const int i = (bid - 90) * 256 + t;
        if (i < a.degn) a.deg[i] = 0;
    }
}

// ---------------------------------------------------------------------------
// k_fA (r12): FULL-WIDTH GEMM L0 + XCD-SLICED histogram, one launch.
// r11 exposed scatter/hist atomics as cross-XCD coherence victims. Slicing:
// block with absolute s=blockIdx&7 (round-robin ->XCD, m09) handles ONLY
// dst in [s*6250,(s+1)*6250) of a 4096-edge slab -> deg words single-XCD,
// atomics L2-local. Extra dst re-reads (8x, streamed) hide under the gemm.
// ---------------------------------------------------------------------------
__global__ __launch_bounds__(512) void k_fA(const void* __restrict__ Xv,
                                            const int* __restrict__ xflag,
                                            const u16* __restrict__ Wp,
                                            u16* __restrict__ OUT, int nrows,
                                            const int* __restrict__ dstv,
                                            int* __restrict__ deg, int E) {
    __shared__ u16 As[64 * 256];   // 32 KB
    const int gblocks = (nrows + 63) >> 6;
    if ((int)blockIdx.x >= gblocks) {
        const int i = blockIdx.x - gblocks;
        const int s = blockIdx.x & 7;          // absolute id -> XCD
        const int g = i >> 3;
        const int lo = s * SLICE, hi = lo + SLICE;
        const int base = g * 4096;
#pragma unroll
        for (int k = 0; k < 8; ++k) {
            const int e = base + k * 512 + threadIdx.x;
            if (e < E) {
                const int dv = dstv[e];
                if (dv >= lo && dv < hi) atomicAdd(&deg[dv], 1);
            }
        }
        return;
    }
    const int t = threadIdx.x;
    const int w = t >> 6, L = t & 63;
    const int quad = (L >> 4) & 3;
    const int r0 = blockIdx.x * 64;
    const bool xf32 = (xflag != nullptr) && (*xflag == 1);

    short8* Asv = (short8*)As;
    short8 zero = {0, 0, 0, 0, 0, 0, 0, 0};
#pragma unroll
    for (int i = 0; i < 4; ++i) {
        int g = i * 512 + t;
        int row = g >> 5, cc = g & 31;
        int r = r0 + row;
        short8 val = zero;
        if (r < nrows) {
            if (xf32) {
                const f32x4* Xf4 = (const f32x4*)Xv;
                f32x4 lo = Xf4[(size_t)r * 64 + cc * 2];
                f32x4 hi = Xf4[(size_t)r * 64 + cc * 2 + 1];
                val[0] = (short)f2bf(lo[0]); val[1] = (short)f2bf(lo[1]);
                val[2] = (short)f2bf(lo[2]); val[3] = (short)f2bf(lo[3]);
                val[4] = (short)f2bf(hi[0]); val[5] = (short)f2bf(hi[1]);
                val[6] = (short)f2bf(hi[2]); val[7] = (short)f2bf(hi[3]);
            } else {
                val = ((const short8*)Xv)[(size_t)r * 32 + cc];
            }
        }
        Asv[cc * 64 + (row ^ (cc & 7))] = val;
    }

    const short8* Wv = (const short8*)Wp;
    short8 bf[2][8];
#pragma unroll
    for (int jn = 0; jn < 2; ++jn) {
        int nt = w + jn * 8;
#pragma unroll
        for (int kt = 0; kt < 8; ++kt) bf[jn][kt] = Wv[(nt * 8 + kt) * 64 + L];
    }
    __syncthreads();

    f32x4 acc[4][2];
#pragma unroll
    for (int mi = 0; mi < 4; ++mi)
#pragma unroll
        for (int jn = 0; jn < 2; ++jn) acc[mi][jn] = (f32x4){0.f, 0.f, 0.f, 0.f};

#pragma unroll
    for (int kt = 0; kt < 8; ++kt) {
        const int ccr = kt * 4 + quad;
#pragma unroll
        for (int mi = 0; mi < 4; ++mi) {
            short8 af = Asv[ccr * 64 + ((mi * 16 + (L & 15)) ^ (ccr & 7))];
            acc[mi][0] = __builtin_amdgcn_mfma_f32_16x16x32_bf16(af, bf[0][kt], acc[mi][0], 0, 0, 0);
            acc[mi][1] = __builtin_amdgcn_mfma_f32_16x16x32_bf16(af, bf[1][kt], acc[mi][1], 0, 0, 0);
        }
    }

#pragma unroll
    for (int mi = 0; mi < 4; ++mi) {
        int rb = r0 + mi * 16 + quad * 4;
#pragma unroll
        for (int jn = 0; jn < 2; ++jn) {
            int c = (w + jn * 8) * 16 + (L & 15);
#pragma unroll
            for (int reg = 0; reg < 4; ++reg) {
                int r = rb + reg;
                if (r < nrows) OUT[(size_t)r * 256 + c] = f2bf(acc[mi][jn][reg]);
            }
        }
    }
}

// ---------------------------------------------------------------------------
// scan: partial sums, then final (bsum scan folded into final).
// ---------------------------------------------------------------------------
__global__ __launch_bounds__(256) void k_scan_partial(const int* __restrict__ deg,
                                                      int* __restrict__ bsum, int n) {
    __shared__ int red[256];
    int t = threadIdx.x;
    int i = blockIdx.x * 256 + t;
    red[t] = (i < n) ? deg[i] : 0;
    __syncthreads();
    for (int ofs = 128; ofs > 0; ofs >>= 1) {
        if (t < ofs) red[t] += red[t + ofs];
        __syncthreads();
    }
    if (t == 0) bsum[blockIdx.x] = red[0];
}

__global__ __launch_bounds__(256) void k_scan_final(const int* __restrict__ deg,
                                                    const int* __restrict__ bsum,
                                                    int* __restrict__ rowptr,
                                                    int* __restrict__ cursor,
                                                    int n, int nb) {
    __shared__ int s[256], bs[256];
    int t = threadIdx.x;
    bs[t] = (t < nb) ? bsum[t] : 0;
    __syncthreads();
    for (int ofs = 1; ofs < 256; ofs <<= 1) {
        int x = (t >= ofs) ? bs[t - ofs] : 0;
        __syncthreads();
        bs[t] += x;
        __syncthreads();
    }
    const int bexcl = (blockIdx.x == 0) ? 0 : bs[blockIdx.x - 1];

    int i = blockIdx.x * 256 + t;
    int v = (i < n) ? deg[i] : 0;
    s[t] = v;
    __syncthreads();
    for (int ofs = 1; ofs < 256; ofs <<= 1) {
        int x = (t >= ofs) ? s[t - ofs] : 0;
        __syncthreads();
        s[t] += x;
        __syncthreads();
    }
    int excl = bexcl + s[t] - v;
    if (i < n) {
        rowptr[i] = excl;
        cursor[i] = excl;
        if (i == n - 1) rowptr[n] = excl + v;
    }
}

// ---------------------------------------------------------------------------
// k_fB (r12): XCD-SLICED scatter + elr8(L0), one launch.
// Scatter block s=blockIdx&7 (XCD) scans a 2048-edge slab, processes only
// dst in its slice -> cursor atomics L2-local (return round-trip ~200cy not
// ~900), csr_src lines single-XCD-owned (kills the 9x write amplification
// r11 measured: WRITE 57MB for 6.4MB payload). Blocks [0,3128): scatter;
// rest: elr8.
// ---------------------------------------------------------------------------
__global__ __launch_bounds__(256) void k_fB(const int* __restrict__ src,
                                            const int* __restrict__ dstv,
                                            int* __restrict__ cursor,
                                            int* __restrict__ csr_src, int E,
                                            const u16* __restrict__ featb,
                                            const float* __restrict__ al,
                                            const float* __restrict__ ar,
                                            float* __restrict__ el,
                                            float* __restrict__ er, int n) {
    const int nsc = 391 * 8;   // 391 slabs x 8 slices, slab = 2048 edges
    if ((int)blockIdx.x < nsc) {
        const int s = blockIdx.x & 7;          // absolute id -> XCD
        const int g = blockIdx.x >> 3;
        const int lo = s * SLICE, hi = lo + SLICE;
        const int base = g * 2048;
#pragma unroll
        for (int k = 0; k < 8; ++k) {
            const int e = base + k * 256 + threadIdx.x;
            if (e < E) {
                const int dv = dstv[e];
                if (dv >= lo && dv < hi) {
                    int p = atomicAdd(&cursor[dv], 1);
                    csr_src[p] = src[e];
                }
            }
        }
        return;
    }
    const int idx = (blockIdx.x - nsc) * 256 + threadIdx.x;
    if (idx >= n * 8) return;
    const int node = idx >> 3, h = idx & 7;
    const u32v4* fu = (const u32v4*)((const u32*)featb + (size_t)node * 128 + h * 16);
    const float* A = al + h * 32;
    const float* B = ar + h * 32;
    float sl = 0.f, sr = 0.f;
#pragma unroll
    for (int j = 0; j < 4; ++j) {
        u32v4 w4 = fu[j];
#pragma unroll
        for (int k = 0; k < 4; ++k) {
            u32 w = (k == 0) ? w4.x : (k == 1) ? w4.y : (k == 2) ? w4.z : w4.w;
            float f0 = bflo(w), f1 = bfhi(w);
            int c = j * 8 + k * 2;
            sl += f0 * A[c] + f1 * A[c + 1];
            sr += f0 * B[c] + f1 * B[c + 1];
        }
    }
    el[idx] = sl;
    er[idx] = sr;
}

// ---------------------------------------------------------------------------
// MFMA GEMM (FULL-WIDTH, r9): standalone for layer 1. X staged ONCE;
// As XOR-swizzled.
// ---------------------------------------------------------------------------
__global__ __launch_bounds__(512) void k_gemm_mfma(const void* __restrict__ Xv,
                                                   const int* __restrict__ xflag,
                                                   const u16* __restrict__ Wp,
                                                   u16* __restrict__ OUT, int nrows) {
    __shared__ u16 As[64 * 256];   // 32 KB
    const int t = threadIdx.x;
    const int w = t >> 6, L = t & 63;
    const int quad = (L >> 4) & 3;
    const int r0 = blockIdx.x * 64;
    const bool xf32 = (xflag != nullptr) && (*xflag == 1);

    short8* Asv = (short8*)As;
    short8 zero = {0, 0, 0, 0, 0, 0, 0, 0};
#pragma unroll
    for (int i = 0; i < 4; ++i) {
        int g = i * 512 + t;
        int row = g >> 5, cc = g & 31;
        int r = r0 + row;
        short8 val = zero;
        if (r < nrows) {
            if (xf32) {
                const f32x4* Xf4 = (const f32x4*)Xv;
                f32x4 lo = Xf4[(size_t)r * 64 + cc * 2];
                f32x4 hi = Xf4[(size_t)r * 64 + cc * 2 + 1];
                val[0] = (short)f2bf(lo[0]); val[1] = (short)f2bf(lo[1]);
                val[2] = (short)f2bf(lo[2]); val[3] = (short)f2bf(lo[3]);
                val[4] = (short)f2bf(hi[0]); val[5] = (short)f2bf(hi[1]);
                val[6] = (short)f2bf(hi[2]); val[7] = (short)f2bf(hi[3]);
            } else {
                val = ((const short8*)Xv)[(size_t)r * 32 + cc];
            }
        }
        Asv[cc * 64 + (row ^ (cc & 7))] = val;
    }

    const short8* Wv = (const short8*)Wp;
    short8 bf[2][8];
#pragma unroll
    for (int jn = 0; jn < 2; ++jn) {
        int nt = w + jn * 8;
#pragma unroll
        for (int kt = 0; kt < 8; ++kt) bf[jn][kt] = Wv[(nt * 8 + kt) * 64 + L];
    }
    __syncthreads();

    f32x4 acc[4][2];
#pragma unroll
    for (int mi = 0; mi < 4; ++mi)
#pragma unroll
        for (int jn = 0; jn < 2; ++jn) acc[mi][jn] = (f32x4){0.f, 0.f, 0.f, 0.f};

#pragma unroll
    for (int kt = 0; kt < 8; ++kt) {
        const int ccr = kt * 4 + quad;
#pragma unroll
        for (int mi = 0; mi < 4; ++mi) {
            short8 af = Asv[ccr * 64 + ((mi * 16 + (L & 15)) ^ (ccr & 7))];
            acc[mi][0] = __builtin_amdgcn_mfma_f32_16x16x32_bf16(af, bf[0][kt], acc[mi][0], 0, 0, 0);
            acc[mi][1] = __builtin_amdgcn_mfma_f32_16x16x32_bf16(af, bf[1][kt], acc[mi][1], 0, 0, 0);
        }
    }

#pragma unroll
    for (int mi = 0; mi < 4; ++mi) {
        int rb = r0 + mi * 16 + quad * 4;
#pragma unroll
        for (int jn = 0; jn < 2; ++jn) {
            int c = (w + jn * 8) * 16 + (L & 15);
#pragma unroll
            for (int reg = 0; reg < 4; ++reg) {
                int r = rb + reg;
                if (r < nrows) OUT[(size_t)r * 256 + c] = f2bf(acc[mi][jn][reg]);
            }
        }
    }
}

// MFMA GEMM layer 2: [nrows,256](bf16) x Wp2 -> bf16 [nrows,32]. BM=128, BN=32.
__global__ __launch_bounds__(256) void k_gemm_mfma32(const u16* __restrict__ Xb,
                                                     const u16* __restrict__ Wp,
                                                     u16* __restrict__ OUT, int nrows) {
    __shared__ u16 As[128 * 256];  // 64 KB
    const int t = threadIdx.x;
    const int w = t >> 6, L = t & 63;
    const int quad = (L >> 4) & 3;
    const int r0 = blockIdx.x * 128;
    const int mh = (w >> 1) * 64, nt = w & 1;

    const short8* Xv = (const short8*)Xb;
    short8* Asv = (short8*)As;
    short8 zero = {0, 0, 0, 0, 0, 0, 0, 0};
#pragma unroll
    for (int i = 0; i < 16; ++i) {
        int g = i * 256 + t;
        int row = g >> 5, cc = g & 31;
        int r = r0 + row;
        Asv[cc * 128 + (row ^ (cc & 7))] = (r < nrows) ? Xv[(size_t)r * 32 + cc] : zero;
    }

    const short8* Wv = (const short8*)Wp;
    short8 bf[8];
#pragma unroll
    for (int kt = 0; kt < 8; ++kt) bf[kt] = Wv[(nt * 8 + kt) * 64 + L];
    __syncthreads();

    f32x4 acc[4];
#pragma unroll
    for (int mi = 0; mi < 4; ++mi) acc[mi] = (f32x4){0.f, 0.f, 0.f, 0.f};

#pragma unroll
    for (int kt = 0; kt < 8; ++kt) {
        const int ccr = kt * 4 + quad;
#pragma unroll
        for (int mi = 0; mi < 4; ++mi) {
            short8 af = Asv[ccr * 128 + ((mh + mi * 16 + (L & 15)) ^ (ccr & 7))];
            acc[mi] = __builtin_amdgcn_mfma_f32_16x16x32_bf16(af, bf[kt], acc[mi], 0, 0, 0);
        }
    }

#pragma unroll
    for (int mi = 0; mi < 4; ++mi) {
        int rb = r0 + mh + mi * 16 + quad * 4;
        int c = nt * 16 + (L & 15);
#pragma unroll
        for (int reg = 0; reg < 4; ++reg) {
            int r = rb + reg;
            if (r < nrows) OUT[(size_t)r * 32 + c] = f2bf(acc[mi][reg]);
        }
    }
}

// attention logit dots (feat bf16 node-major, dwordx4 loads) — layer 1
__global__ void k_elr8(const u16* __restrict__ featb, const float* __restrict__ al,
                       const float* __restrict__ ar, float* __restrict__ el,
                       float* __restrict__ er, int n) {
    int idx = blockIdx.x * 256 + threadIdx.x;
    if (idx >= n * 8) return;
    int node = idx >> 3, h = idx & 7;
    const u32v4* fu = (const u32v4*)((const u32*)featb + (size_t)node * 128 + h * 16);
    const float* A = al + h * 32;
    const float* B = ar + h * 32;
    float sl = 0.f, sr = 0.f;
#pragma unroll
    for (int j = 0; j < 4; ++j) {
        u32v4 w4 = fu[j];
#pragma unroll
        for (int k = 0; k < 4; ++k) {
            u32 w = (k == 0) ? w4.x : (k == 1) ? w4.y : (k == 2) ? w4.z : w4.w;
            float f0 = bflo(w), f1 = bfhi(w);
            int c = j * 8 + k * 2;
            sl += f0 * A[c] + f1 * A[c + 1];
            sr += f0 * B[c] + f1 * B[c + 1];
        }
    }
    el[idx] = sl;
    er[idx] = sr;
}

__global__ void k_elr1(const u16* __restrict__ featb, const float* __restrict__ al,
                       const float* __restrict__ ar, float* __restrict__ el,
                       float* __restrict__ er, int n) {
    int node = blockIdx.x * 256 + threadIdx.x;
    if (node >= n) return;
    const u32v4* fu = (const u32v4*)((const u32*)featb + (size_t)node * 16);
    float sl = 0.f, sr = 0.f;
#pragma unroll
    for (int j = 0; j < 4; ++j) {
        u32v4 w4 = fu[j];
#pragma unroll
        for (int k = 0; k < 4; ++k) {
            u32 w = (k == 0) ? w4.x : (k == 1) ? w4.y : (k == 2) ? w4.z : w4.w;
            float f0 = bflo(w), f1 = bfhi(w);
            int c = j * 8 + k * 2;
            sl += f0 * al[c] + f1 * al[c + 1];
            sr += f0 * ar[c] + f1 * ar[c + 1];
        }
    }
    el[node] = sl;
    er[node] = sr;
}

// ---------------------------------------------------------------------------
// fused softmax+gather: ONE WAVE PER NODE (64 lanes x dwordx2 = 4 cols/lane),
// software-pipelined 8-edge chunks (MEASURED-BEST, seven rounds stable:
// 65.5us @ 209MB / 3.67TB/s = the random-512B-chunk L3->L2 fill ceiling).
// ---------------------------------------------------------------------------
__global__ __launch_bounds__(256) void k_gather8(const int* __restrict__ rowptr,
                                                 const int* __restrict__ csr_src,
                                                 const float* __restrict__ el,
                                                 const float* __restrict__ er,
                                                 const u32v2* __restrict__ featb4,
                                                 const float* __restrict__ bias,
                                                 u32v2* __restrict__ xout4) {
    __shared__ __align__(16) float sAL[4][2][64];   // [wave][buf][h*8+e]
    __shared__ __align__(16) int   sSL[4][2][8];    // [wave][buf][e]
    const int t = threadIdx.x;
    const int wv = t >> 6;
    const int q = t & 63;            // owns cols 4q..4q+3, head h = q>>3
    const int d = blockIdx.x * 4 + wv;
    const int eL = q >> 3, hL = q & 7;   // producer role: edge eL, head hL
    const int b = rowptr[d], e = rowptr[d + 1];
    const int deg = e - b;
    const int nch = (deg + 7) >> 3;
    const float erA = er[d * 8 + hL];

    float (*AL)[64] = sAL[wv];
    int (*SL)[8] = sSL[wv];

    float a0 = 0.f, a1 = 0.f, a2 = 0.f, a3 = 0.f;
    float partial = 0.f;

    u32v2 fw[8], fw2[8];
    int csrP = 0, ncP = 0;
    float elP = 0.f;

    if (nch > 0) {
        // prologue: stage chunk 0 fully; issue chunk-1 csr + el
        const int nc0 = deg < 8 ? deg : 8;
        const int i0 = eL < nc0 ? eL : nc0 - 1;
        const int s0 = csr_src[b + i0];
        if (nch > 1) {
            const int r1 = deg - 8;
            ncP = r1 < 8 ? r1 : 8;
            const int i1 = eL < ncP ? eL : ncP - 1;
            csrP = csr_src[b + 8 + i1];
        }
        const float el0 = el[s0 * 8 + hL];
        if (hL == 0) SL[0][eL] = s0;
        const int4 sv0 = *(const int4*)&SL[0][0];
        const int4 sv1 = *(const int4*)&SL[0][4];
        fw[0] = featb4[sv0.x * 64 + q];
        fw[1] = featb4[sv0.y * 64 + q];
        fw[2] = featb4[sv0.z * 64 + q];
        fw[3] = featb4[sv0.w * 64 + q];
        fw[4] = featb4[sv1.x * 64 + q];
        fw[5] = featb4[sv1.y * 64 + q];
        fw[6] = featb4[sv1.z * 64 + q];
        fw[7] = featb4[sv1.w * 64 + q];
        const float ex0 = (eL < nc0) ? lexp(el0 + erA) : 0.f;
        partial += ex0;
        AL[0][hL * 8 + eL] = ex0;
        if (nch > 1) elP = el[csrP * 8 + hL];
    }

    for (int c = 0; c < nch; ++c) {
        const int cur = c & 1, nxt = cur ^ 1;

        // issue csr for chunk c+2 (2-deep so c+1's el issue never stalls)
        int csrF = 0, ncF = 0;
        if (c + 2 < nch) {
            const int r2 = deg - (c + 2) * 8;
            ncF = r2 < 8 ? r2 : 8;
            const int i2 = eL < ncF ? eL : ncF - 1;
            csrF = csr_src[b + (c + 2) * 8 + i2];
        }

        // stage chunk c+1: s-list -> LDS -> feat issues; alpha -> LDS
        if (c + 1 < nch) {
            if (hL == 0) SL[nxt][eL] = csrP;
            const int4 sv0 = *(const int4*)&SL[nxt][0];
            const int4 sv1 = *(const int4*)&SL[nxt][4];
            fw2[0] = featb4[sv0.x * 64 + q];
            fw2[1] = featb4[sv0.y * 64 + q];
            fw2[2] = featb4[sv0.z * 64 + q];
            fw2[3] = featb4[sv0.w * 64 + q];
            fw2[4] = featb4[sv1.x * 64 + q];
            fw2[5] = featb4[sv1.y * 64 + q];
            fw2[6] = featb4[sv1.z * 64 + q];
            fw2[7] = featb4[sv1.w * 64 + q];
            const float exN = (eL < ncP) ? lexp(elP + erA) : 0.f;
            partial += exN;
            AL[nxt][hL * 8 + eL] = exN;
        }

        // read alpha chunk c (broadcast ds_read_b128 x2, conflict-free)
        const int h8 = (q >> 3) * 8;
        const f32x4 A0 = *(const f32x4*)&AL[cur][h8];
        const f32x4 A1 = *(const f32x4*)&AL[cur][h8 + 4];

        // issue el for chunk c+2 (elP consumed above; safe to overwrite)
        if (c + 2 < nch) elP = el[csrF * 8 + hL];

        // FMA chunk c (feat issued one full chunk ago -> latency hidden)
#define GAT_EDGE(i, axv) { const u32v2 w_ = fw[i]; \
        a0 += bflo(w_.x) * (axv); a1 += bfhi(w_.x) * (axv); \
        a2 += bflo(w_.y) * (axv); a3 += bfhi(w_.y) * (axv); }
        GAT_EDGE(0, A0[0]) GAT_EDGE(1, A0[1]) GAT_EDGE(2, A0[2]) GAT_EDGE(3, A0[3])
        GAT_EDGE(4, A1[0]) GAT_EDGE(5, A1[1]) GAT_EDGE(6, A1[2]) GAT_EDGE(7, A1[3])
#undef GAT_EDGE

        // rotate pipeline state
#pragma unroll
        for (int i = 0; i < 8; ++i) fw[i] = fw2[i];
        csrP = csrF;
        ncP = ncF;
    }

    // denominator: reduce producer partials across eL (bits 3..5), then
    // fetch the consumer head's sum from lane (q>>3)
    float v = partial;
    v += __shfl_xor(v, 8);
    v += __shfl_xor(v, 16);
    v += __shfl_xor(v, 32);
    const float ssd = __shfl(v, q >> 3);

    const float rd = 1.f / (ssd + 1e-9f);
    const float4 bb = *(const float4*)&bias[4 * q];
    float v0 = a0 * rd + bb.x;
    float v1 = a1 * rd + bb.y;
    float v2 = a2 * rd + bb.z;
    float v3 = a3 * rd + bb.w;
    v0 = v0 > 0.f ? v0 : expm1f(v0);
    v1 = v1 > 0.f ? v1 : expm1f(v1);
    v2 = v2 > 0.f ? v2 : expm1f(v2);
    v3 = v3 > 0.f ? v3 : expm1f(v3);
    u32v2 o;
    o.x = (u32)f2bf(v0) | ((u32)f2bf(v1) << 16);
    o.y = (u32)f2bf(v2) | ((u32)f2bf(v3) << 16);
    xout4[(size_t)d * 64 + q] = o;
}

// layer-2 fused gather (pipelined form).
__global__ __launch_bounds__(256) void k_gather1(const int* __restrict__ rowptr,
                                                 const int* __restrict__ csr_src,
                                                 const float* __restrict__ el,
                                                 const float* __restrict__ er,
                                                 const u32* __restrict__ featb2,
                                                 const float* __restrict__ bias,
                                                 void* __restrict__ out,
                                                 const int* __restrict__ flag, int n) {
    const int t = threadIdx.x;
    const int d = blockIdx.x * 16 + (t >> 4);
    const int lane = t & 15;          // owns cols 2*lane, 2*lane+1
    if (d >= n) return;
    const int b = rowptr[d], e = rowptr[d + 1];
    const float erd = er[d];
    float a0 = 0.f, a1 = 0.f, ssum = 0.f;

    for (int c = b; c < e; c += 16) {
        const int idx = c + lane;
        const int s_own = csr_src[idx < e ? idx : e - 1];
        const float ex_own = (idx < e) ? lexp(el[s_own] + erd) : 0.f;
        ssum += ex_own;
#pragma unroll
        for (int i = 0; i < 16; ++i) {
            const int si = __shfl(s_own, i, 16);
            const float ai = __shfl(ex_own, i, 16);
            const u32 w = featb2[(size_t)si * 16 + lane];
            a0 += bflo(w) * ai;
            a1 += bfhi(w) * ai;
        }
    }

    ssum += __shfl_xor(ssum, 1);
    ssum += __shfl_xor(ssum, 2);
    ssum += __shfl_xor(ssum, 4);
    ssum += __shfl_xor(ssum, 8);

    const float rd = 1.f / (ssum + 1e-9f);
    const float v0 = a0 * rd + bias[2 * lane];
    const float v1 = a1 * rd + bias[2 * lane + 1];
    if (*flag == 1) {
        f32x2 o = {v0, v1};
        ((f32x2*)out)[(size_t)d * 16 + lane] = o;
    } else {
        ((u32*)out)[(size_t)d * 16 + lane] = (u32)f2bf(v0) | ((u32)f2bf(v1) << 16);
    }
}

extern "C" void kernel_launch(void* const* d_in, const int* in_sizes, int n_in,
                              void* d_out, int out_size, void* d_ws, size_t ws_size,
                              hipStream_t stream) {
    const void* features = d_in[0];
    const int* src = (const int*)d_in[1];
    const int* dst = (const int*)d_in[2];

    char* ws = (char*)d_ws;
    size_t off = 0;
    auto carve = [&](size_t bytes) -> void* {
        void* p = ws + off;
        off = (off + bytes + 255) & ~(size_t)255;
        return p;
    };
    int*   flags = (int*)carve(64);
    float* pconv = (float*)carve(2048 * 4);
    u16*   Wp0 = (u16*)carve(65536 * 2);
    u16*   Wp1 = (u16*)carve(65536 * 2);
    u16*   Wp2 = (u16*)carve(8192 * 2);
    u16*   Xb    = (u16*)carve((size_t)NN * 256 * 2);  // bf16 hidden state
    u16*   featb = (u16*)carve((size_t)NN * 256 * 2);  // bf16 GEMM output
    float* el   = (float*)carve((size_t)NN * 8 * 4);
    float* er   = (float*)carve((size_t)NN * 8 * 4);
    int*   deg     = (int*)carve((size_t)NN * 4);
    int*   cursor  = (int*)carve((size_t)NN * 4);
    int*   rowptr  = (int*)carve((size_t)(NN + 1) * 4);
    int*   bsum    = (int*)carve(256 * 4);
    int*   csr_src = (int*)carve((size_t)NE * 4);
    if (off > ws_size) return;  // clean ws-too-small signature

    const int N = NN, E = NE;
    const int nscan = (N + 255) / 256;   // 196 <= 256

    // ---- merged prep: detect + convert + wpack x3 + deg-zero, ONE launch ----
    PrepArgs pa;
    const int din_idx[13] = {0, 3, 4, 5, 6, 7, 8, 9, 10, 11, 12, 13, 14};
    for (int j = 0; j < 13; ++j) {
        pa.dp[j] = (const u32*)d_in[din_idx[j]];
        int nw = in_sizes[din_idx[j]] / 2;
        pa.dnw[j] = nw > 512 ? 512 : nw;
    }
    const int psl[9] = {4, 5, 6, 8, 9, 10, 12, 13, 14};
    float* dsts[9];
    {
        size_t o = 0;
        for (int j = 0; j < 9; ++j) {
            dsts[j] = pconv + o;
            o += (size_t)in_sizes[psl[j]];
        }
    }
    for (int j = 0; j < 9; ++j) {
        pa.cs[j] = d_in[psl[j]];
        pa.cd[j] = dsts[j];
        pa.cn[j] = in_sizes[psl[j]];
    }
    pa.wsrc[0] = d_in[3];  pa.wdst[0] = Wp0; pa.wN[0] = 256; pa.wchunks[0] = 8192;
    pa.wsrc[1] = d_in[7];  pa.wdst[1] = Wp1; pa.wN[1] = 256; pa.wchunks[1] = 8192;
    pa.wsrc[2] = d_in[11]; pa.wdst[2] = Wp2; pa.wN[2] = 32;  pa.wchunks[2] = 1024;
    pa.deg = deg; pa.degn = N;
    k_prep<<<90 + nscan, 256, 0, stream>>>(pa, flags);
    float* al0f = dsts[0]; float* ar0f = dsts[1]; float* b0f = dsts[2];
    float* al1f = dsts[3]; float* ar1f = dsts[4]; float* b1f = dsts[5];
    float* al2f = dsts[6]; float* ar2f = dsts[7]; float* b2f = dsts[8];

    const int ggrid = (N + 63) / 64;           // 782 gemm blocks
    const int hblocks = 196 * 8;               // sliced hist: 196 slabs x 8

    // ---- layer 0 gemm + XCD-sliced CSR hist, ONE launch ----
    k_fA<<<ggrid + hblocks, 512, 0, stream>>>(features, flags, Wp0, featb, N,
                                              dst, deg, E);

    // scan (partial -> final; bsum folded into final)
    k_scan_partial<<<nscan, 256, 0, stream>>>(deg, bsum, N);
    k_scan_final<<<nscan, 256, 0, stream>>>(deg, bsum, rowptr, cursor, N, nscan);

    // ---- XCD-sliced scatter + elr8 L0, ONE launch ----
    const int scb = 391 * 8;                   // sliced scatter blocks
    const int elb = (N * 8 + 255) / 256;       // 1563 elr8 blocks
    k_fB<<<scb + elb, 256, 0, stream>>>(src, dst, cursor, csr_src, E,
                                        featb, al0f, ar0f, el, er, N);

    k_gather8<<<N / 4, 256, 0, stream>>>(rowptr, csr_src, el, er,
                                         (const u32v2*)featb, b0f, (u32v2*)Xb);

    // ---------------- layer 1 ----------------
    k_gemm_mfma<<<ggrid, 512, 0, stream>>>(Xb, nullptr, Wp1, featb, N);
    k_elr8<<<elb, 256, 0, stream>>>(featb, al1f, ar1f, el, er, N);
    k_gather8<<<N / 4, 256, 0, stream>>>(rowptr, csr_src, el, er,
                                         (const u32v2*)featb, b1f, (u32v2*)Xb);

    // ---------------- layer 2 (1 head, D=32) ----------------
    k_gemm_mfma32<<<(N + 127) / 128, 256, 0, stream>>>(Xb, Wp2, featb, N);
    k_elr1<<<(N + 255) / 256, 256, 0, stream>>>(featb, al2f, ar2f, el, er, N);
    k_gather1<<<(N + 15) / 16, 256, 0, stream>>>(rowptr, csr_src, el, er,
                                                 (const u32*)featb, b2f,
                                                 d_out, flags, N);
}

// Round 14
// 398.308 us; speedup vs baseline: 1.0583x; 1.0030x over previous
//
#include <hip/hip_runtime.h>

typedef unsigned short u16;
typedef unsigned int   u32;
typedef __attribute__((ext_vector_type(8))) short  short8;
typedef __attribute__((ext_vector_type(4))) float  f32x4;
typedef __attribute__((ext_vector_type(2))) float  f32x2;
typedef __attribute__((ext_vector_type(2))) unsigned int u32v2;
typedef __attribute__((ext_vector_type(4))) unsigned int u32v4;

#define NN 50000
#define NE 800000
#define SLICE 6250   // NN/8 nodes per XCD slice

__device__ __forceinline__ float bf2f(u16 b) { return __uint_as_float(((u32)b) << 16); }
__device__ __forceinline__ float bflo(u32 p) { return __uint_as_float(p << 16); }
__device__ __forceinline__ float bfhi(u32 p) { return __uint_as_float(p & 0xffff0000u); }
__device__ __forceinline__ u16 f2bf(float f) {
    u32 u = __float_as_uint(f);
    u32 r = u + 0x7fffu + ((u >> 16) & 1u);
    return (u16)(r >> 16);
}
// leaky-relu + clamped exp (clamp is identity for this data's logit range)
__device__ __forceinline__ float lexp(float v) {
    v = fmaxf(v, 0.2f * v);
    return __expf(fminf(v, 60.f));
}

// block-wide dtype detect (0=bf16, 1=fp32, 2=all-zero) from a 512-word
// prefix; result valid in ALL threads (reduction ends with syncthreads).
__device__ __forceinline__ int block_detect(const u32* x, int n, int* sh, int* sz) {
    int t = threadIdx.x;
    int hits = 0, nz = 0;
    for (int i = t; i < n; i += 256) {
        u32 w = x[i];
        if (w) {
            ++nz;
            u32 e = (w >> 7) & 0xffu;
            if (e >= 100 && e <= 150) ++hits;
        }
    }
    sh[t] = hits; sz[t] = nz;
    __syncthreads();
    for (int ofs = 128; ofs > 0; ofs >>= 1) {
        if (t < ofs) { sh[t] += sh[t + ofs]; sz[t] += sz[t + ofs]; }
        __syncthreads();
    }
    return (sz[0] == 0) ? 2 : ((sh[0] * 2 >= sz[0]) ? 0 : 1);
}

// ---------------------------------------------------------------------------
// k_prep: detect(13) + convert(9) + wpack x3 + deg-zeroing, ONE launch.
// ---------------------------------------------------------------------------
struct PrepArgs {
    const u32* dp[13]; int dnw[13];                 // detect
    const void* cs[9]; float* cd[9]; int cn[9];     // convert (n <= 256)
    const void* wsrc[3]; u16* wdst[3]; int wN[3]; int wchunks[3];  // wpack
    int* deg; int degn;                             // deg zeroing
};

__global__ __launch_bounds__(256) void k_prep(PrepArgs a, int* flags) {
    __shared__ int sh[256], sz[256];
    const int bid = blockIdx.x;
    const int t = threadIdx.x;
    if (bid < 13) {
        int f = block_detect(a.dp[bid], a.dnw[bid], sh, sz);
        if (t == 0) flags[bid] = f;
    } else if (bid < 22) {
        const int j = bid - 13;
        int nw = a.cn[j] / 2; if (nw > 512) nw = 512;
        const int fl = block_detect((const u32*)a.cs[j], nw, sh, sz);
        if (t < a.cn[j]) {
            float v = 0.f;
            if (fl == 1) v = ((const float*)a.cs[j])[t];
            else if (fl == 0) v = bf2f(((const u16*)a.cs[j])[t]);
            a.cd[j][t] = v;
        }
    } else if (bid < 90) {
        int wj, base;
        if (bid < 54)      { wj = 0; base = 22; }
        else if (bid < 86) { wj = 1; base = 54; }
        else               { wj = 2; base = 86; }
        const void* Wsrc = a.wsrc[wj];
        const int fl = block_detect((const u32*)Wsrc, 512, sh, sz);
        const int id = (bid - base) * 256 + t;
        if (id < a.wchunks[wj]) {
            const int L = id & 63, kt = (id >> 6) & 7, nt = id >> 9;
            const int col = nt * 16 + (L & 15);
            const int krow = kt * 32 + ((L >> 4) & 3) * 8;
            const bool isf32 = (fl == 1);
            const int N = a.wN[wj];
            u16* Wp = a.wdst[wj];
#pragma unroll
            for (int j2 = 0; j2 < 8; ++j2) {
                int s = (krow + j2) * N + col;
                Wp[id * 8 + j2] = isf32 ? f2bf(((const float*)Wsrc)[s])
                                        : ((const u16*)Wsrc)[s];
            }
        }
    } else {
        const int i = (bid - 90) * 256 + t;
        if (i < a.degn) a.deg[i] = 0;
    }
}

// ---------------------------------------------------------------------------
// k_fA: FULL-WIDTH GEMM L0 + XCD-SLICED histogram, one launch (r12,
// verified). Block with absolute s=blockIdx&7 handles only dst in its
// slice of a 4096-edge slab -> deg atomics L2-local.
// ---------------------------------------------------------------------------
__global__ __launch_bounds__(512) void k_fA(const void* __restrict__ Xv,
                                            const int* __restrict__ xflag,
                                            const u16* __restrict__ Wp,
                                            u16* __restrict__ OUT, int nrows,
                                            const int* __restrict__ dstv,
                                            int* __restrict__ deg, int E) {
    __shared__ u16 As[64 * 256];   // 32 KB
    const int gblocks = (nrows + 63) >> 6;
    if ((int)blockIdx.x >= gblocks) {
        const int i = blockIdx.x - gblocks;
        const int s = blockIdx.x & 7;          // absolute id -> XCD
        const int g = i >> 3;
        const int lo = s * SLICE, hi = lo + SLICE;
        const int base = g * 4096;
#pragma unroll
        for (int k = 0; k < 8; ++k) {
            const int e = base + k * 512 + threadIdx.x;
            if (e < E) {
                const int dv = dstv[e];
                if (dv >= lo && dv < hi) atomicAdd(&deg[dv], 1);
            }
        }
        return;
    }
    const int t = threadIdx.x;
    const int w = t >> 6, L = t & 63;
    const int quad = (L >> 4) & 3;
    const int r0 = blockIdx.x * 64;
    const bool xf32 = (xflag != nullptr) && (*xflag == 1);

    short8* Asv = (short8*)As;
    short8 zero = {0, 0, 0, 0, 0, 0, 0, 0};
#pragma unroll
    for (int i = 0; i < 4; ++i) {
        int g = i * 512 + t;
        int row = g >> 5, cc = g & 31;
        int r = r0 + row;
        short8 val = zero;
        if (r < nrows) {
            if (xf32) {
                const f32x4* Xf4 = (const f32x4*)Xv;
                f32x4 lo = Xf4[(size_t)r * 64 + cc * 2];
                f32x4 hi = Xf4[(size_t)r * 64 + cc * 2 + 1];
                val[0] = (short)f2bf(lo[0]); val[1] = (short)f2bf(lo[1]);
                val[2] = (short)f2bf(lo[2]); val[3] = (short)f2bf(lo[3]);
                val[4] = (short)f2bf(hi[0]); val[5] = (short)f2bf(hi[1]);
                val[6] = (short)f2bf(hi[2]); val[7] = (short)f2bf(hi[3]);
            } else {
                val = ((const short8*)Xv)[(size_t)r * 32 + cc];
            }
        }
        Asv[cc * 64 + (row ^ (cc & 7))] = val;
    }

    const short8* Wv = (const short8*)Wp;
    short8 bf[2][8];
#pragma unroll
    for (int jn = 0; jn < 2; ++jn) {
        int nt = w + jn * 8;
#pragma unroll
        for (int kt = 0; kt < 8; ++kt) bf[jn][kt] = Wv[(nt * 8 + kt) * 64 + L];
    }
    __syncthreads();

    f32x4 acc[4][2];
#pragma unroll
    for (int mi = 0; mi < 4; ++mi)
#pragma unroll
        for (int jn = 0; jn < 2; ++jn) acc[mi][jn] = (f32x4){0.f, 0.f, 0.f, 0.f};

#pragma unroll
    for (int kt = 0; kt < 8; ++kt) {
        const int ccr = kt * 4 + quad;
#pragma unroll
        for (int mi = 0; mi < 4; ++mi) {
            short8 af = Asv[ccr * 64 + ((mi * 16 + (L & 15)) ^ (ccr & 7))];
            acc[mi][0] = __builtin_amdgcn_mfma_f32_16x16x32_bf16(af, bf[0][kt], acc[mi][0], 0, 0, 0);
            acc[mi][1] = __builtin_amdgcn_mfma_f32_16x16x32_bf16(af, bf[1][kt], acc[mi][1], 0, 0, 0);
        }
    }

#pragma unroll
    for (int mi = 0; mi < 4; ++mi) {
        int rb = r0 + mi * 16 + quad * 4;
#pragma unroll
        for (int jn = 0; jn < 2; ++jn) {
            int c = (w + jn * 8) * 16 + (L & 15);
#pragma unroll
            for (int reg = 0; reg < 4; ++reg) {
                int r = rb + reg;
                if (r < nrows) OUT[(size_t)r * 256 + c] = f2bf(acc[mi][jn][reg]);
            }
        }
    }
}

// ---------------------------------------------------------------------------
// scan: partial sums, then final (bsum scan folded into final).
// ---------------------------------------------------------------------------
__global__ __launch_bounds__(256) void k_scan_partial(const int* __restrict__ deg,
                                                      int* __restrict__ bsum, int n) {
    __shared__ int red[256];
    int t = threadIdx.x;
    int i = blockIdx.x * 256 + t;
    red[t] = (i < n) ? deg[i] : 0;
    __syncthreads();
    for (int ofs = 128; ofs > 0; ofs >>= 1) {
        if (t < ofs) red[t] += red[t + ofs];
        __syncthreads();
    }
    if (t == 0) bsum[blockIdx.x] = red[0];
}

__global__ __launch_bounds__(256) void k_scan_final(const int* __restrict__ deg,
                                                    const int* __restrict__ bsum,
                                                    int* __restrict__ rowptr,
                                                    int* __restrict__ cursor,
                                                    int n, int nb) {
    __shared__ int s[256], bs[256];
    int t = threadIdx.x;
    bs[t] = (t < nb) ? bsum[t] : 0;
    __syncthreads();
    for (int ofs = 1; ofs < 256; ofs <<= 1) {
        int x = (t >= ofs) ? bs[t - ofs] : 0;
        __syncthreads();
        bs[t] += x;
        __syncthreads();
    }
    const int bexcl = (blockIdx.x == 0) ? 0 : bs[blockIdx.x - 1];

    int i = blockIdx.x * 256 + t;
    int v = (i < n) ? deg[i] : 0;
    s[t] = v;
    __syncthreads();
    for (int ofs = 1; ofs < 256; ofs <<= 1) {
        int x = (t >= ofs) ? s[t - ofs] : 0;
        __syncthreads();
        s[t] += x;
        __syncthreads();
    }
    int excl = bexcl + s[t] - v;
    if (i < n) {
        rowptr[i] = excl;
        cursor[i] = excl;
        if (i == n - 1) rowptr[n] = excl + v;
    }
}

// ---------------------------------------------------------------------------
// k_fB: XCD-SLICED scatter + elr8(L0), one launch (r12, verified).
// ---------------------------------------------------------------------------
__global__ __launch_bounds__(256) void k_fB(const int* __restrict__ src,
                                            const int* __restrict__ dstv,
                                            int* __restrict__ cursor,
                                            int* __restrict__ csr_src, int E,
                                            const u16* __restrict__ featb,
                                            const float* __restrict__ al,
                                            const float* __restrict__ ar,
                                            float* __restrict__ el,
                                            float* __restrict__ er, int n) {
    const int nsc = 391 * 8;   // 391 slabs x 8 slices, slab = 2048 edges
    if ((int)blockIdx.x < nsc) {
        const int s = blockIdx.x & 7;          // absolute id -> XCD
        const int g = blockIdx.x >> 3;
        const int lo = s * SLICE, hi = lo + SLICE;
        const int base = g * 2048;
#pragma unroll
        for (int k = 0; k < 8; ++k) {
            const int e = base + k * 256 + threadIdx.x;
            if (e < E) {
                const int dv = dstv[e];
                if (dv >= lo && dv < hi) {
                    int p = atomicAdd(&cursor[dv], 1);
                    csr_src[p] = src[e];
                }
            }
        }
        return;
    }
    const int idx = (blockIdx.x - nsc) * 256 + threadIdx.x;
    if (idx >= n * 8) return;
    const int node = idx >> 3, h = idx & 7;
    const u32v4* fu = (const u32v4*)((const u32*)featb + (size_t)node * 128 + h * 16);
    const float* A = al + h * 32;
    const float* B = ar + h * 32;
    float sl = 0.f, sr = 0.f;
#pragma unroll
    for (int j = 0; j < 4; ++j) {
        u32v4 w4 = fu[j];
#pragma unroll
        for (int k = 0; k < 4; ++k) {
            u32 w = (k == 0) ? w4.x : (k == 1) ? w4.y : (k == 2) ? w4.z : w4.w;
            float f0 = bflo(w), f1 = bfhi(w);
            int c = j * 8 + k * 2;
            sl += f0 * A[c] + f1 * A[c + 1];
            sr += f0 * B[c] + f1 * B[c + 1];
        }
    }
    el[idx] = sl;
    er[idx] = sr;
}

// ---------------------------------------------------------------------------
// MFMA GEMM (FULL-WIDTH): standalone for layer 1.
// ---------------------------------------------------------------------------
__global__ __launch_bounds__(512) void k_gemm_mfma(const void* __restrict__ Xv,
                                                   const int* __restrict__ xflag,
                                                   const u16* __restrict__ Wp,
                                                   u16* __restrict__ OUT, int nrows) {
    __shared__ u16 As[64 * 256];   // 32 KB
    const int t = threadIdx.x;
    const int w = t >> 6, L = t & 63;
    const int quad = (L >> 4) & 3;
    const int r0 = blockIdx.x * 64;
    const bool xf32 = (xflag != nullptr) && (*xflag == 1);

    short8* Asv = (short8*)As;
    short8 zero = {0, 0, 0, 0, 0, 0, 0, 0};
#pragma unroll
    for (int i = 0; i < 4; ++i) {
        int g = i * 512 + t;
        int row = g >> 5, cc = g & 31;
        int r = r0 + row;
        short8 val = zero;
        if (r < nrows) {
            if (xf32) {
                const f32x4* Xf4 = (const f32x4*)Xv;
                f32x4 lo = Xf4[(size_t)r * 64 + cc * 2];
                f32x4 hi = Xf4[(size_t)r * 64 + cc * 2 + 1];
                val[0] = (short)f2bf(lo[0]); val[1] = (short)f2bf(lo[1]);
                val[2] = (short)f2bf(lo[2]); val[3] = (short)f2bf(lo[3]);
                val[4] = (short)f2bf(hi[0]); val[5] = (short)f2bf(hi[1]);
                val[6] = (short)f2bf(hi[2]); val[7] = (short)f2bf(hi[3]);
            } else {
                val = ((const short8*)Xv)[(size_t)r * 32 + cc];
            }
        }
        Asv[cc * 64 + (row ^ (cc & 7))] = val;
    }

    const short8* Wv = (const short8*)Wp;
    short8 bf[2][8];
#pragma unroll
    for (int jn = 0; jn < 2; ++jn) {
        int nt = w + jn * 8;
#pragma unroll
        for (int kt = 0; kt < 8; ++kt) bf[jn][kt] = Wv[(nt * 8 + kt) * 64 + L];
    }
    __syncthreads();

    f32x4 acc[4][2];
#pragma unroll
    for (int mi = 0; mi < 4; ++mi)
#pragma unroll
        for (int jn = 0; jn < 2; ++jn) acc[mi][jn] = (f32x4){0.f, 0.f, 0.f, 0.f};

#pragma unroll
    for (int kt = 0; kt < 8; ++kt) {
        const int ccr = kt * 4 + quad;
#pragma unroll
        for (int mi = 0; mi < 4; ++mi) {
            short8 af = Asv[ccr * 64 + ((mi * 16 + (L & 15)) ^ (ccr & 7))];
            acc[mi][0] = __builtin_amdgcn_mfma_f32_16x16x32_bf16(af, bf[0][kt], acc[mi][0], 0, 0, 0);
            acc[mi][1] = __builtin_amdgcn_mfma_f32_16x16x32_bf16(af, bf[1][kt], acc[mi][1], 0, 0, 0);
        }
    }

#pragma unroll
    for (int mi = 0; mi < 4; ++mi) {
        int rb = r0 + mi * 16 + quad * 4;
#pragma unroll
        for (int jn = 0; jn < 2; ++jn) {
            int c = (w + jn * 8) * 16 + (L & 15);
#pragma unroll
            for (int reg = 0; reg < 4; ++reg) {
                int r = rb + reg;
                if (r < nrows) OUT[(size_t)r * 256 + c] = f2bf(acc[mi][jn][reg]);
            }
        }
    }
}

// MFMA GEMM layer 2: [nrows,256](bf16) x Wp2 -> bf16 [nrows,32]. BM=128, BN=32.
__global__ __launch_bounds__(256) void k_gemm_mfma32(const u16* __restrict__ Xb,
                                                     const u16* __restrict__ Wp,
                                                     u16* __restrict__ OUT, int nrows) {
    __shared__ u16 As[128 * 256];  // 64 KB
    const int t = threadIdx.x;
    const int w = t >> 6, L = t & 63;
    const int quad = (L >> 4) & 3;
    const int r0 = blockIdx.x * 128;
    const int mh = (w >> 1) * 64, nt = w & 1;

    const short8* Xv = (const short8*)Xb;
    short8* Asv = (short8*)As;
    short8 zero = {0, 0, 0, 0, 0, 0, 0, 0};
#pragma unroll
    for (int i = 0; i < 16; ++i) {
        int g = i * 256 + t;
        int row = g >> 5, cc = g & 31;
        int r = r0 + row;
        Asv[cc * 128 + (row ^ (cc & 7))] = (r < nrows) ? Xv[(size_t)r * 32 + cc] : zero;
    }

    const short8* Wv = (const short8*)Wp;
    short8 bf[8];
#pragma unroll
    for (int kt = 0; kt < 8; ++kt) bf[kt] = Wv[(nt * 8 + kt) * 64 + L];
    __syncthreads();

    f32x4 acc[4];
#pragma unroll
    for (int mi = 0; mi < 4; ++mi) acc[mi] = (f32x4){0.f, 0.f, 0.f, 0.f};

#pragma unroll
    for (int kt = 0; kt < 8; ++kt) {
        const int ccr = kt * 4 + quad;
#pragma unroll
        for (int mi = 0; mi < 4; ++mi) {
            short8 af = Asv[ccr * 128 + ((mh + mi * 16 + (L & 15)) ^ (ccr & 7))];
            acc[mi] = __builtin_amdgcn_mfma_f32_16x16x32_bf16(af, bf[kt], acc[mi], 0, 0, 0);
        }
    }

#pragma unroll
    for (int mi = 0; mi < 4; ++mi) {
        int rb = r0 + mh + mi * 16 + quad * 4;
        int c = nt * 16 + (L & 15);
#pragma unroll
        for (int reg = 0; reg < 4; ++reg) {
            int r = rb + reg;
            if (r < nrows) OUT[(size_t)r * 32 + c] = f2bf(acc[mi][reg]);
        }
    }
}

// attention logit dots (feat bf16 node-major, dwordx4 loads) — layer 1
__global__ void k_elr8(const u16* __restrict__ featb, const float* __restrict__ al,
                       const float* __restrict__ ar, float* __restrict__ el,
                       float* __restrict__ er, int n) {
    int idx = blockIdx.x * 256 + threadIdx.x;
    if (idx >= n * 8) return;
    int node = idx >> 3, h = idx & 7;
    const u32v4* fu = (const u32v4*)((const u32*)featb + (size_t)node * 128 + h * 16);
    const float* A = al + h * 32;
    const float* B = ar + h * 32;
    float sl = 0.f, sr = 0.f;
#pragma unroll
    for (int j = 0; j < 4; ++j) {
        u32v4 w4 = fu[j];
#pragma unroll
        for (int k = 0; k < 4; ++k) {
            u32 w = (k == 0) ? w4.x : (k == 1) ? w4.y : (k == 2) ? w4.z : w4.w;
            float f0 = bflo(w), f1 = bfhi(w);
            int c = j * 8 + k * 2;
            sl += f0 * A[c] + f1 * A[c + 1];
            sr += f0 * B[c] + f1 * B[c + 1];
        }
    }
    el[idx] = sl;
    er[idx] = sr;
}

__global__ void k_elr1(const u16* __restrict__ featb, const float* __restrict__ al,
                       const float* __restrict__ ar, float* __restrict__ el,
                       float* __restrict__ er, int n) {
    int node = blockIdx.x * 256 + threadIdx.x;
    if (node >= n) return;
    const u32v4* fu = (const u32v4*)((const u32*)featb + (size_t)node * 16);
    float sl = 0.f, sr = 0.f;
#pragma unroll
    for (int j = 0; j < 4; ++j) {
        u32v4 w4 = fu[j];
#pragma unroll
        for (int k = 0; k < 4; ++k) {
            u32 w = (k == 0) ? w4.x : (k == 1) ? w4.y : (k == 2) ? w4.z : w4.w;
            float f0 = bflo(w), f1 = bfhi(w);
            int c = j * 8 + k * 2;
            sl += f0 * al[c] + f1 * al[c + 1];
            sr += f0 * ar[c] + f1 * ar[c + 1];
        }
    }
    el[node] = sl;
    er[node] = sr;
}

// ---------------------------------------------------------------------------
// fused softmax+gather: ONE WAVE PER NODE, software-pipelined 8-edge chunks.
// r13 VALU diet on the proven r1 structure (co-limited: VALU 65% + fill at
// the 3.67TB/s random-512B ceiling; cutting wave instrs probes whether the
// marginal binder is issue or fill):
//  1) ping-pong fwA/fwB via 2x unroll -> kills 16 v_mov rotation/chunk
//  2) SL stores s*64 (pre-scaled featb4 index) -> kills 8 lshl/chunk
// Semantics identical. If dur doesn't move, gather8 is purely fill-bound.
// ---------------------------------------------------------------------------
__global__ __launch_bounds__(256) void k_gather8(const int* __restrict__ rowptr,
                                                 const int* __restrict__ csr_src,
                                                 const float* __restrict__ el,
                                                 const float* __restrict__ er,
                                                 const u32v2* __restrict__ featb4,
                                                 const float* __restrict__ bias,
                                                 u32v2* __restrict__ xout4) {
    __shared__ __align__(16) float sAL[4][2][64];   // [wave][buf][h*8+e]
    __shared__ __align__(16) int   sSL[4][2][8];    // [wave][buf][e] (s*64)
    const int t = threadIdx.x;
    const int wv = t >> 6;
    const int q = t & 63;            // owns cols 4q..4q+3, head h = q>>3
    const int d = blockIdx.x * 4 + wv;
    const int eL = q >> 3, hL = q & 7;   // producer role: edge eL, head hL
    const int b = rowptr[d], e = rowptr[d + 1];
    const int deg = e - b;
    const int nch = (deg + 7) >> 3;
    const float erA = er[d * 8 + hL];

    float (*AL)[64] = sAL[wv];
    int (*SL)[8] = sSL[wv];

    float a0 = 0.f, a1 = 0.f, a2 = 0.f, a3 = 0.f;
    float partial = 0.f;

    u32v2 fwA[8], fwB[8];
    int csrP = 0, ncP = 0;
    float elP = 0.f;

    if (nch > 0) {
        // prologue: stage chunk 0 fully into fwA; issue chunk-1 csr + el
        const int nc0 = deg < 8 ? deg : 8;
        const int i0 = eL < nc0 ? eL : nc0 - 1;
        const int s0 = csr_src[b + i0];
        if (nch > 1) {
            const int r1 = deg - 8;
            ncP = r1 < 8 ? r1 : 8;
            const int i1 = eL < ncP ? eL : ncP - 1;
            csrP = csr_src[b + 8 + i1];
        }
        const float el0 = el[s0 * 8 + hL];
        if (hL == 0) SL[0][eL] = s0 * 64;
        const int4 sv0 = *(const int4*)&SL[0][0];
        const int4 sv1 = *(const int4*)&SL[0][4];
        fwA[0] = featb4[sv0.x + q];
        fwA[1] = featb4[sv0.y + q];
        fwA[2] = featb4[sv0.z + q];
        fwA[3] = featb4[sv0.w + q];
        fwA[4] = featb4[sv1.x + q];
        fwA[5] = featb4[sv1.y + q];
        fwA[6] = featb4[sv1.z + q];
        fwA[7] = featb4[sv1.w + q];
        const float ex0 = (eL < nc0) ? lexp(el0 + erA) : 0.f;
        partial += ex0;
        AL[0][hL * 8 + eL] = ex0;
        if (nch > 1) elP = el[csrP * 8 + hL];
    }

    // one pipeline step: consume fwc (chunk c), stage chunk c+1 into fwn
    auto step = [&](u32v2 (&fwc)[8], u32v2 (&fwn)[8], int c) {
        const int cur = c & 1, nxt = cur ^ 1;

        // issue csr for chunk c+2 (2-deep so c+1's el issue never stalls)
        int csrF = 0, ncF = 0;
        if (c + 2 < nch) {
            const int r2 = deg - (c + 2) * 8;
            ncF = r2 < 8 ? r2 : 8;
            const int i2 = eL < ncF ? eL : ncF - 1;
            csrF = csr_src[b + (c + 2) * 8 + i2];
        }

        // stage chunk c+1: s*64-list -> LDS -> feat issues; alpha -> LDS
        if (c + 1 < nch) {
            if (hL == 0) SL[nxt][eL] = csrP * 64;
            const int4 sv0 = *(const int4*)&SL[nxt][0];
            const int4 sv1 = *(const int4*)&SL[nxt][4];
            fwn[0] = featb4[sv0.x + q];
            fwn[1] = featb4[sv0.y + q];
            fwn[2] = featb4[sv0.z + q];
            fwn[3] = featb4[sv0.w + q];
            fwn[4] = featb4[sv1.x + q];
            fwn[5] = featb4[sv1.y + q];
            fwn[6] = featb4[sv1.z + q];
            fwn[7] = featb4[sv1.w + q];
            const float exN = (eL < ncP) ? lexp(elP + erA) : 0.f;
            partial += exN;
            AL[nxt][hL * 8 + eL] = exN;
        }

        // read alpha chunk c (broadcast ds_read_b128 x2, conflict-free)
        const int h8 = (q >> 3) * 8;
        const f32x4 A0 = *(const f32x4*)&AL[cur][h8];
        const f32x4 A1 = *(const f32x4*)&AL[cur][h8 + 4];

        // issue el for chunk c+2 (elP consumed above; safe to overwrite)
        if (c + 2 < nch) elP = el[csrF * 8 + hL];

        // FMA chunk c (feat issued one full chunk ago -> latency hidden)
#define GAT_EDGE(i, axv) { const u32v2 w_ = fwc[i]; \
        a0 += bflo(w_.x) * (axv); a1 += bfhi(w_.x) * (axv); \
        a2 += bflo(w_.y) * (axv); a3 += bfhi(w_.y) * (axv); }
        GAT_EDGE(0, A0[0]) GAT_EDGE(1, A0[1]) GAT_EDGE(2, A0[2]) GAT_EDGE(3, A0[3])
        GAT_EDGE(4, A1[0]) GAT_EDGE(5, A1[1]) GAT_EDGE(6, A1[2]) GAT_EDGE(7, A1[3])
#undef GAT_EDGE

        csrP = csrF;
        ncP = ncF;
    };

    for (int c = 0; c < nch; c += 2) {
        step(fwA, fwB, c);
        if (c + 1 < nch) step(fwB, fwA, c + 1);
    }

    // denominator: reduce producer partials across eL (bits 3..5), then
    // fetch the consumer head's sum from lane (q>>3)
    float v = partial;
    v += __shfl_xor(v, 8);
    v += __shfl_xor(v, 16);
    v += __shfl_xor(v, 32);
    const float ssd = __shfl(v, q >> 3);

    const float rd = 1.f / (ssd + 1e-9f);
    const float4 bb = *(const float4*)&bias[4 * q];
    float v0 = a0 * rd + bb.x;
    float v1 = a1 * rd + bb.y;
    float v2 = a2 * rd + bb.z;
    float v3 = a3 * rd + bb.w;
    v0 = v0 > 0.f ? v0 : expm1f(v0);
    v1 = v1 > 0.f ? v1 : expm1f(v1);
    v2 = v2 > 0.f ? v2 : expm1f(v2);
    v3 = v3 > 0.f ? v3 : expm1f(v3);
    u32v2 o;
    o.x = (u32)f2bf(v0) | ((u32)f2bf(v1) << 16);
    o.y = (u32)f2bf(v2) | ((u32)f2bf(v3) << 16);
    xout4[(size_t)d * 64 + q] = o;
}

// layer-2 fused gather (pipelined form).
__global__ __launch_bounds__(256) void k_gather1(const int* __restrict__ rowptr,
                                                 const int* __restrict__ csr_src,
                                                 const float* __restrict__ el,
                                                 const float* __restrict__ er,
                                                 const u32* __restrict__ featb2,
                                                 const float* __restrict__ bias,
                                                 void* __restrict__ out,
                                                 const int* __restrict__ flag, int n) {
    const int t = threadIdx.x;
    const int d = blockIdx.x * 16 + (t >> 4);
    const int lane = t & 15;          // owns cols 2*lane, 2*lane+1
    if (d >= n) return;
    const int b = rowptr[d], e = rowptr[d + 1];
    const float erd = er[d];
    float a0 = 0.f, a1 = 0.f, ssum = 0.f;

    for (int c = b; c < e; c += 16) {
        const int idx = c + lane;
        const int s_own = csr_src[idx < e ? idx : e - 1];
        const float ex_own = (idx < e) ? lexp(el[s_own] + erd) : 0.f;
        ssum += ex_own;
#pragma unroll
        for (int i = 0; i < 16; ++i) {
            const int si = __shfl(s_own, i, 16);
            const float ai = __shfl(ex_own, i, 16);
            const u32 w = featb2[(size_t)si * 16 + lane];
            a0 += bflo(w) * ai;
            a1 += bfhi(w) * ai;
        }
    }

    ssum += __shfl_xor(ssum, 1);
    ssum += __shfl_xor(ssum, 2);
    ssum += __shfl_xor(ssum, 4);
    ssum += __shfl_xor(ssum, 8);

    const float rd = 1.f / (ssum + 1e-9f);
    const float v0 = a0 * rd + bias[2 * lane];
    const float v1 = a1 * rd + bias[2 * lane + 1];
    if (*flag == 1) {
        f32x2 o = {v0, v1};
        ((f32x2*)out)[(size_t)d * 16 + lane] = o;
    } else {
        ((u32*)out)[(size_t)d * 16 + lane] = (u32)f2bf(v0) | ((u32)f2bf(v1) << 16);
    }
}

extern "C" void kernel_launch(void* const* d_in, const int* in_sizes, int n_in,
                              void* d_out, int out_size, void* d_ws, size_t ws_size,
                              hipStream_t stream) {
    const void* features = d_in[0];
    const int* src = (const int*)d_in[1];
    const int* dst = (const int*)d_in[2];

    char* ws = (char*)d_ws;
    size_t off = 0;
    auto carve = [&](size_t bytes) -> void* {
        void* p = ws + off;
        off = (off + bytes + 255) & ~(size_t)255;
        return p;
    };
    int*   flags = (int*)carve(64);
    float* pconv = (float*)carve(2048 * 4);
    u16*   Wp0 = (u16*)carve(65536 * 2);
    u16*   Wp1 = (u16*)carve(65536 * 2);
    u16*   Wp2 = (u16*)carve(8192 * 2);
    u16*   Xb    = (u16*)carve((size_t)NN * 256 * 2);  // bf16 hidden state
    u16*   featb = (u16*)carve((size_t)NN * 256 * 2);  // bf16 GEMM output
    float* el   = (float*)carve((size_t)NN * 8 * 4);
    float* er   = (float*)carve((size_t)NN * 8 * 4);
    int*   deg     = (int*)carve((size_t)NN * 4);
    int*   cursor  = (int*)carve((size_t)NN * 4);
    int*   rowptr  = (int*)carve((size_t)(NN + 1) * 4);
    int*   bsum    = (int*)carve(256 * 4);
    int*   csr_src = (int*)carve((size_t)NE * 4);
    if (off > ws_size) return;  // clean ws-too-small signature

    const int N = NN, E = NE;
    const int nscan = (N + 255) / 256;   // 196 <= 256

    // ---- merged prep: detect + convert + wpack x3 + deg-zero, ONE launch ----
    PrepArgs pa;
    const int din_idx[13] = {0, 3, 4, 5, 6, 7, 8, 9, 10, 11, 12, 13, 14};
    for (int j = 0; j < 13; ++j) {
        pa.dp[j] = (const u32*)d_in[din_idx[j]];
        int nw = in_sizes[din_idx[j]] / 2;
        pa.dnw[j] = nw > 512 ? 512 : nw;
    }
    const int psl[9] = {4, 5, 6, 8, 9, 10, 12, 13, 14};
    float* dsts[9];
    {
        size_t o = 0;
        for (int j = 0; j < 9; ++j) {
            dsts[j] = pconv + o;
            o += (size_t)in_sizes[psl[j]];
        }
    }
    for (int j = 0; j < 9; ++j) {
        pa.cs[j] = d_in[psl[j]];
        pa.cd[j] = dsts[j];
        pa.cn[j] = in_sizes[psl[j]];
    }
    pa.wsrc[0] = d_in[3];  pa.wdst[0] = Wp0; pa.wN[0] = 256; pa.wchunks[0] = 8192;
    pa.wsrc[1] = d_in[7];  pa.wdst[1] = Wp1; pa.wN[1] = 256; pa.wchunks[1] = 8192;
    pa.wsrc[2] = d_in[11]; pa.wdst[2] = Wp2; pa.wN[2] = 32;  pa.wchunks[2] = 1024;
    pa.deg = deg; pa.degn = N;
    k_prep<<<90 + nscan, 256, 0, stream>>>(pa, flags);
    float* al0f = dsts[0]; float* ar0f = dsts[1]; float* b0f = dsts[2];
    float* al1f = dsts[3]; float* ar1f = dsts[4]; float* b1f = dsts[5];
    float* al2f = dsts[6]; float* ar2f = dsts[7]; float* b2f = dsts[8];

    const int ggrid = (N + 63) / 64;           // 782 gemm blocks
    const int hblocks = 196 * 8;               // sliced hist: 196 slabs x 8

    // ---- layer 0 gemm + XCD-sliced CSR hist, ONE launch ----
    k_fA<<<ggrid + hblocks, 512, 0, stream>>>(features, flags, Wp0, featb, N,
                                              dst, deg, E);

    // scan (partial -> final; bsum folded into final)
    k_scan_partial<<<nscan, 256, 0, stream>>>(deg, bsum, N);
    k_scan_final<<<nscan, 256, 0, stream>>>(deg, bsum, rowptr, cursor, N, nscan);

    // ---- XCD-sliced scatter + elr8 L0, ONE launch ----
    const int scb = 391 * 8;                   // sliced scatter blocks
    const int elb = (N * 8 + 255) / 256;       // 1563 elr8 blocks
    k_fB<<<scb + elb, 256, 0, stream>>>(src, dst, cursor, csr_src, E,
                                        featb, al0f, ar0f, el, er, N);

    k_gather8<<<N / 4, 256, 0, stream>>>(rowptr, csr_src, el, er,
                                         (const u32v2*)featb, b0f, (u32v2*)Xb);

    // ---------------- layer 1 ----------------
    k_gemm_mfma<<<ggrid, 512, 0, stream>>>(Xb, nullptr, Wp1, featb, N);
    k_elr8<<<elb, 256, 0, stream>>>(featb, al1f, ar1f, el, er, N);
    k_gather8<<<N / 4, 256, 0, stream>>>(rowptr, csr_src, el, er,
                                         (const u32v2*)featb, b1f, (u32v2*)Xb);

    // ---------------- layer 2 (1 head, D=32) ----------------
    k_gemm_mfma32<<<(N + 127) / 128, 256, 0, stream>>>(Xb, Wp2, featb, N);
    k_elr1<<<(N + 255) / 256, 256, 0, stream>>>(featb, al2f, ar2f, el, er, N);
    k_gather1<<<(N + 15) / 16, 256, 0, stream>>>(rowptr, csr_src, el, er,
                                                 (const u32*)featb, b2f,
                                                 d_out, flags, N);
}